// Round 4
// baseline (1001.334 us; speedup 1.0000x reference)
//
#include <hip/hip_runtime.h>
#include <stdint.h>

// ---------------------------------------------------------------------------
// BGCGRU on MI355X: all heavy ops as bf16 MFMA NT-GEMMs (fp32 accumulate).
//   aggregation  C[m,f] = sum_n S[m,n]   * X[f,n]   (X spatial-contiguous)
//   projection   C[c,n] = sum_f W^T[c,f] * Y[n,f]   (Y feature-contiguous)
// Round 4: batch z folded into N (pow2 decode in epilogue) so every GEMM is
// one large 2D GEMM; ring-4 LDS staging pipeline with COUNTED vmcnt waits
// (T4): stage(t+3) issued each iter, s_waitcnt vmcnt(3*LPT) + raw s_barrier,
// never draining to 0 in steady state. XOR bank swizzle retained.
// ---------------------------------------------------------------------------

typedef __bf16 bf16;
typedef float  f32x4  __attribute__((ext_vector_type(4)));
typedef __bf16 bf16x8 __attribute__((ext_vector_type(8)));
typedef __bf16 bf16x4v __attribute__((ext_vector_type(4)));

#define DEVI __device__ __forceinline__

DEVI void gload16(const bf16* g, bf16* l) {
  __builtin_amdgcn_global_load_lds(
      (const __attribute__((address_space(1))) void*)g,
      (__attribute__((address_space(3))) void*)l, 16, 0, 0);
}
template<int N> DEVI void vm_wait() {
  asm volatile("s_waitcnt vmcnt(%0)" :: "n"(N) : "memory");
}
DEVI void lgkm0() { asm volatile("s_waitcnt lgkmcnt(0)" ::: "memory"); }

struct GemmArgs {
  const bf16* A; const bf16* B;
  bf16* Cn;   // normal write:  [z] row-major [m][col], nullable
  bf16* Ct;   // transposed:    [z] row-major [col][m], nullable
  int lda, ldb, ldcn, ldct, K, zshB, zshC;
  long sB, sCn, sCt;   // per-z element strides
};

struct TaskDesc { GemmArgs g; int kind, gx, blk0, nblk; };
struct MultiArgs { TaskDesc t[2]; int nt; };

// Ring-4 pipelined NT GEMM. 4 waves (2x2), 16x16x32 bf16 MFMA, BK=32.
// Counted vmcnt: 3 tiles stay in flight across barriers (T4).
template<int BM, int BN>
DEVI void gemm_body(const GemmArgs& g, int bx, int by, bf16* smem) {
  constexpr int BK  = 32;
  constexpr int LPT = BM / 64 + BN / 64;      // gload16 per thread per stage
  constexpr int ASZ = BM * BK, BSZ = BN * BK;
  bf16* Abuf = smem;
  bf16* Bbuf = smem + 4 * ASZ;
  const int tid  = threadIdx.x;
  const int wave = tid >> 6;
  const int lane = tid & 63;
  const int wm = (wave >> 1) * (BM / 2);
  const int wn = (wave & 1) * (BN / 2);
  constexpr int FM = BM / 32;
  constexpr int FN = BN / 32;

  const int srow = tid >> 2;                                // staging row
  const int sseg = ((lane & 3) ^ ((lane >> 3) & 3)) * 8;    // swz source seg
  const int l15  = lane & 15;
  const int kof  = ((lane >> 4) ^ ((lane >> 1) & 3)) * 8;   // swz read seg

  // Loop-invariant per-thread global row pointers (z-fold decode for B).
  const bf16* arow[BM / 64];
  #pragma unroll
  for (int c = 0; c < BM / 64; ++c)
    arow[c] = g.A + (long)(bx * BM + c * 64 + srow) * g.lda + sseg;
  const bf16* brow[BN / 64];
  const int maskB = (1 << g.zshB) - 1;
  #pragma unroll
  for (int c = 0; c < BN / 64; ++c) {
    const int nb = by * BN + c * 64 + srow;
    brow[c] = g.B + (long)(nb >> g.zshB) * g.sB + (long)(nb & maskB) * g.ldb + sseg;
  }

  f32x4 acc[FM][FN] = {};

  auto stage = [&](int buf, int kt) {
    #pragma unroll
    for (int c = 0; c < BM / 64; ++c)
      gload16(arow[c] + kt, &Abuf[buf * ASZ + (c * 64 + wave * 16) * BK]);
    #pragma unroll
    for (int c = 0; c < BN / 64; ++c)
      gload16(brow[c] + kt, &Bbuf[buf * BSZ + (c * 64 + wave * 16) * BK]);
  };
  auto compute = [&](int cb) {
    bf16x8 af[FM], bfr[FN];
    #pragma unroll
    for (int i = 0; i < FM; ++i)
      af[i] = *(const bf16x8*)&Abuf[cb * ASZ + (wm + i * 16 + l15) * BK + kof];
    #pragma unroll
    for (int j = 0; j < FN; ++j)
      bfr[j] = *(const bf16x8*)&Bbuf[cb * BSZ + (wn + j * 16 + l15) * BK + kof];
    #pragma unroll
    for (int i = 0; i < FM; ++i)
      #pragma unroll
      for (int j = 0; j < FN; ++j)
        acc[i][j] = __builtin_amdgcn_mfma_f32_16x16x32_bf16(af[i], bfr[j],
                                                            acc[i][j], 0, 0, 0);
  };

  const int nt = g.K / BK;
  stage(0, 0);
  if (nt > 1) stage(1, BK);
  if (nt > 2) stage(2, 2 * BK);

  int t = 0;
  for (; t < nt - 3; ++t) {             // steady state: 3 tiles in flight
    stage((t + 3) & 3, (t + 3) * BK);
    vm_wait<3 * LPT>();                 // tile t landed; t+1..t+3 in flight
    __builtin_amdgcn_sched_barrier(0);
    __builtin_amdgcn_s_barrier();
    __builtin_amdgcn_sched_barrier(0);
    compute(t & 3);
    lgkm0();                            // reads of buf[t&3] retired
    __builtin_amdgcn_sched_barrier(0);
    __builtin_amdgcn_s_barrier();       // safe to overwrite buf[t&3] next iter
    __builtin_amdgcn_sched_barrier(0);
  }
  for (; t < nt; ++t) {                 // drain
    const int rem = nt - 1 - t;
    if (rem == 2) vm_wait<2 * LPT>();
    else if (rem == 1) vm_wait<1 * LPT>();
    else vm_wait<0>();
    __builtin_amdgcn_sched_barrier(0);
    __builtin_amdgcn_s_barrier();
    __builtin_amdgcn_sched_barrier(0);
    compute(t & 3);
    lgkm0();
    __builtin_amdgcn_sched_barrier(0);
    __builtin_amdgcn_s_barrier();
    __builtin_amdgcn_sched_barrier(0);
  }

  // Epilogue. C/D layout (m89-verified): col = lane&15, row = (lane>>4)*4+r.
  const int gm0 = bx * BM + wm;
  const int gn0 = by * BN + wn;
  const int rowq = (lane >> 4) * 4;
  const int maskC = (1 << g.zshC) - 1;
  if (g.Cn) {
    #pragma unroll
    for (int i = 0; i < FM; ++i)
      #pragma unroll
      for (int j = 0; j < FN; ++j) {
        const int m0 = gm0 + i * 16 + rowq;
        const int ng = gn0 + j * 16 + l15;
        bf16* Cz = g.Cn + (long)(ng >> g.zshC) * g.sCn + (ng & maskC);
        #pragma unroll
        for (int r = 0; r < 4; ++r)
          Cz[(long)(m0 + r) * g.ldcn] = (bf16)acc[i][j][r];
      }
  }
  if (g.Ct) {
    #pragma unroll
    for (int i = 0; i < FM; ++i)
      #pragma unroll
      for (int j = 0; j < FN; ++j) {
        const int m0 = gm0 + i * 16 + rowq;
        const int ng = gn0 + j * 16 + l15;
        bf16x4v v = { (bf16)acc[i][j][0], (bf16)acc[i][j][1],
                      (bf16)acc[i][j][2], (bf16)acc[i][j][3] };
        *(bf16x4v*)(g.Ct + (long)(ng >> g.zshC) * g.sCt
                    + (long)(ng & maskC) * g.ldct + m0) = v;
      }
  }
}

__global__ __launch_bounds__(256) void gemm_multi(MultiArgs mu) {
  __shared__ bf16 smem[32768];    // 64 KB: ring-4 x (A+B) tile, kind0 size
  const int b = blockIdx.x;
  const int ti = (mu.nt > 1 && b >= mu.t[1].blk0) ? 1 : 0;
  const TaskDesc t = mu.t[ti];
  const int local = b - t.blk0;
  const int bx = local % t.gx;
  const int by = local / t.gx;
  if (t.kind == 0) gemm_body<128, 128>(t.g, bx, by, smem);
  else             gemm_body< 64, 128>(t.g, bx, by, smem);
}

// ---------------- prep / elementwise kernels -------------------------------

__global__ void cvt_pad(const float* in, int R, int C, bf16* out, int Cp) {
  const int r = blockIdx.y;
  const int c = blockIdx.x * blockDim.x + threadIdx.x;
  float v = (r < R && c < C) ? in[(long)r * C + c] : 0.f;
  out[(long)r * Cp + c] = (bf16)v;
}

__global__ void cvt_transpose(const float* in, int R, int C, bf16* out, int ldo) {
  __shared__ float t[64][65];
  const int n0 = blockIdx.x * 64;
  const int e0 = blockIdx.y * 64;
  const int tx = threadIdx.x, ty = threadIdx.y;
  for (int i = ty; i < 64; i += 4) {
    int r = n0 + i, c = e0 + tx;
    t[i][tx] = (r < R && c < C) ? in[(long)r * C + c] : 0.f;
  }
  __syncthreads();
  for (int i = ty; i < 64; i += 4)
    out[(long)(e0 + i) * ldo + n0 + tx] = (bf16)t[tx][i];
}

struct WPrep { const float* W; bf16* WT; int Fin, Fout, ldt; };
struct WAll {
  WPrep w[12];
  const float* aw1; const float* al1; float* s1;
  const float* aw2; const float* al2; float* s2;
};
__global__ void prep_weights(WAll a) {
  const int b = blockIdx.x;
  if (b < 12) {
    WPrep w = a.w[b];
    for (int i = threadIdx.x; i < w.Fout * w.ldt; i += blockDim.x) {
      int c = i / w.ldt, f = i % w.ldt;
      float v = (f < w.Fin) ? w.W[(long)f * w.Fout + c] : 0.f;
      w.WT[i] = (bf16)v;
    }
  } else if (b == 12) {
    for (int f = threadIdx.x; f < 128; f += blockDim.x) {
      float s = 0.f;
      for (int w = 0; w < 128; ++w) s += a.aw1[w * 128 + f] * a.al1[w];
      a.s1[f] = s;
    }
  } else {
    for (int f = threadIdx.x; f < 64; f += blockDim.x) {
      float s = 0.f;
      for (int w = 0; w < 64; ++w) s += a.aw2[w * 64 + f] * a.al2[w];
      a.s2[f] = s;
    }
  }
}

__global__ void build_tem1(const float* x, const float* h, bf16* tem) {
  const int b = blockIdx.y;
  const int i = blockIdx.x * blockDim.x + threadIdx.x;
  const int f = i % 96, n = i / 96;
  float v = 0.f;
  if (n < 2000 && f < 66) {
    if (f < 2) v = x[(long)b * 4000 + n * 2 + f];
    else       v = h[(long)b * 128000 + (long)n * 64 + (f - 2)];
  }
  tem[((long)b * 2048 + n) * 96 + f] = (bf16)v;
}

__global__ void build_tem2(const float* x, const float* h, const bf16* fea,
                           bf16* tem) {
  const int b = blockIdx.y;
  const int i = blockIdx.x * blockDim.x + threadIdx.x;
  const int f = i % 96, n = i / 96;
  float v = 0.f;
  if (n < 2000 && f < 66) {
    if (f < 2) v = x[(long)b * 4000 + n * 2 + f];
    else {
      int co = f - 2;
      float r = (float)fea[((long)b * 2048 + n) * 128 + 64 + co];
      v = (1.f / (1.f + expf(-r))) * h[(long)b * 128000 + (long)n * 64 + co];
    }
  }
  tem[((long)b * 2048 + n) * 96 + f] = (bf16)v;
}

template<int F>
__global__ void attention_k(const bf16* hop0, int ld0, const bf16* hop1, int ld1,
                            const bf16* hop2, int ld2, const float* s, bf16* fea) {
  const int nloc = blockIdx.x * 4 + (threadIdx.x >> 6);
  const int b = blockIdx.y;
  const int lane = threadIdx.x & 63;
  const long bn = (long)b * 2048 + nloc;
  constexpr int NF = F / 64;
  float h0[NF], h1[NF], h2[NF];
  float d0 = 0.f, d1 = 0.f, d2 = 0.f;
  #pragma unroll
  for (int q = 0; q < NF; ++q) {
    int f = lane + q * 64;
    h0[q] = (float)hop0[bn * ld0 + f];
    h1[q] = (float)hop1[bn * ld1 + f];
    h2[q] = (float)hop2[bn * ld2 + f];
    float sv = s[f];
    d0 += h0[q] * sv; d1 += h1[q] * sv; d2 += h2[q] * sv;
  }
  #pragma unroll
  for (int o = 32; o; o >>= 1) {
    d0 += __shfl_xor(d0, o); d1 += __shfl_xor(d1, o); d2 += __shfl_xor(d2, o);
  }
  float mx = fmaxf(d0, fmaxf(d1, d2));
  float e0 = expf(d0 - mx), e1 = expf(d1 - mx), e2 = expf(d2 - mx);
  float inv = 1.f / (e0 + e1 + e2);
  e0 *= inv; e1 *= inv; e2 *= inv;
  #pragma unroll
  for (int q = 0; q < NF; ++q) {
    int f = lane + q * 64;
    fea[bn * F + f] = (bf16)(e0 * h0[q] + e1 * h1[q] + e2 * h2[q]);
  }
}

__global__ void gru_out(const bf16* fea, const bf16* cc, const float* h,
                        float* out) {
  const int b = blockIdx.y;
  const int i = blockIdx.x * blockDim.x + threadIdx.x;
  const int co = i & 63, n = i >> 6;
  float z  = (float)fea[((long)b * 2048 + n) * 128 + co];
  float c  = (float)cc [((long)b * 2048 + n) * 64 + co];
  float hv = h[(long)b * 128000 + i];
  float zs = 1.f / (1.f + expf(-z));
  out[(long)b * 128000 + i] = zs * hv + (1.f - zs) * tanhf(c);
}

__global__ void ws_diag(float* out, int n, float v) {
  int i = blockIdx.x * blockDim.x + threadIdx.x;
  if (i < n) out[i] = v;
}

// ---------------------------------------------------------------------------

static TaskDesc TD(int kind, int gx, int nblk,
                   const bf16* A, int lda,
                   const bf16* B, int ldb, int zshB, long sB,
                   bf16* Cn, int ldcn, long sCn,
                   bf16* Ct, int ldct, long sCt, int zshC, int K) {
  TaskDesc t;
  t.g = GemmArgs{A, B, Cn, Ct, lda, ldb, ldcn, ldct, K, zshB, zshC, sB, sCn, sCt};
  t.kind = kind; t.gx = gx; t.blk0 = 0; t.nblk = nblk;
  return t;
}
static void run1(hipStream_t st, TaskDesc a) {
  MultiArgs m; m.t[0] = a; m.t[0].blk0 = 0; m.nt = 1;
  gemm_multi<<<a.nblk, 256, 0, st>>>(m);
}
static void run2p(hipStream_t st, TaskDesc a, TaskDesc b) {
  MultiArgs m; m.t[0] = a; m.t[0].blk0 = 0;
  m.t[1] = b; m.t[1].blk0 = a.nblk; m.nt = 2;
  gemm_multi<<<a.nblk + b.nblk, 256, 0, st>>>(m);
}

extern "C" void kernel_launch(void* const* d_in, const int* in_sizes, int n_in,
                              void* d_out, int out_size, void* d_ws, size_t ws_size,
                              hipStream_t stream) {
  const float* x    = (const float*)d_in[0];
  const float* hid  = (const float*)d_in[1];
  const float* S0   = (const float*)d_in[2];
  const float* S1   = (const float*)d_in[3];
  const float* M    = (const float*)d_in[4];

  char* base = (char*)d_ws;
  size_t off = 0;
  auto alloc = [&](size_t bytes) -> void* {
    void* r = base + off;
    off += (bytes + 255) & ~(size_t)255;
    return r;
  };

  bf16* S0b = (bf16*)alloc(2048ull * 2048 * 2);
  bf16* S1b = (bf16*)alloc(4096ull * 4096 * 2);
  bf16* Mb  = (bf16*)alloc(2048ull * 4096 * 2);
  bf16* MTb = (bf16*)alloc(4096ull * 2048 * 2);
  bf16* tem = (bf16*)alloc(16ull * 2048 * 96 * 2);
  bf16* ccb = (bf16*)alloc(16ull * 2048 * 64 * 2);

  static const int wd[12][3] = {
    {66,128,96},{66,128,96},{256,128,256},{256,128,256},{128,128,128},{128,128,128},
    {66, 64,96},{66, 64,96},{128, 64,128},{128, 64,128},{ 64, 64, 64},{ 64, 64, 64}};
  static const int wsrc[12] = {5,6,7,8,9,10, 13,14,15,16,17,18};
  bf16* Wt[12];
  for (int i = 0; i < 12; ++i) Wt[i] = (bf16*)alloc((size_t)wd[i][1] * wd[i][2] * 2);
  float* s1 = (float*)alloc(128 * 4);
  float* s2 = (float*)alloc(64 * 4);

  const size_t SLOT = 16ull * 4096 * 128 * 2;  // 16 MB
  char* T0 = (char*)alloc(SLOT);
  char* T1 = (char*)alloc(SLOT);
  char* T2 = (char*)alloc(SLOT);
  char* T3 = (char*)alloc(SLOT);
  char* T4 = (char*)alloc(SLOT);

  if (off > ws_size) {
    ws_diag<<<4, 256, 0, stream>>>((float*)d_out, 1024, (float)(ws_size >> 20));
    return;
  }

  // g1 buffers (liveness identical to round 3):
  bf16* xW    = (bf16*)T0;               // [z][256][2048]
  bf16* eg0   = (bf16*)T1;               // [z][4096][128]
  bf16* cat1  = (bf16*)T2;               // [z][2048][256]
  bf16* eg0p  = (bf16*)T3;               // [z][128][4096]
  bf16* eg1nf = (bf16*)T4;               // [z][4096][128]
  bf16* eg1fn = (bf16*)T0;               // [z][128][4096]
  bf16* eg1p  = (bf16*)T3;               // [z][128][4096]
  bf16* cp1   = (bf16*)T1;               // [z][128][2048]
  bf16* eg2fn = (bf16*)T0;               // [z][128][4096]
  bf16* cat2  = (bf16*)T3;               // [z][2048][256]
  bf16* cp2   = (bf16*)T1;               // [z][128][2048]
  bf16* hop2  = (bf16*)(T1 + 8388608);   // [z][2048][128]
  bf16* feab  = (bf16*)T4;               // [z][2048][128]

  // ---- prep ----
  cvt_pad<<<dim3(8, 2048), 256, 0, stream>>>(S0, 2000, 2000, S0b, 2048);
  cvt_pad<<<dim3(16, 4096), 256, 0, stream>>>(S1, 4000, 4000, S1b, 4096);
  cvt_pad<<<dim3(16, 2048), 256, 0, stream>>>(M, 2000, 4000, Mb, 4096);
  cvt_transpose<<<dim3(32, 64), dim3(64, 4), 0, stream>>>(M, 2000, 4000, MTb, 2048);
  WAll wa;
  for (int i = 0; i < 12; ++i)
    wa.w[i] = WPrep{(const float*)d_in[wsrc[i]], Wt[i], wd[i][0], wd[i][1], wd[i][2]};
  wa.aw1 = (const float*)d_in[11]; wa.al1 = (const float*)d_in[12]; wa.s1 = s1;
  wa.aw2 = (const float*)d_in[19]; wa.al2 = (const float*)d_in[20]; wa.s2 = s2;
  prep_weights<<<14, 256, 0, stream>>>(wa);
  build_tem1<<<dim3(768, 16), 256, 0, stream>>>(x, hid, tem);

  // ---- g1 (F = 128; agg zshC=7, proj zshC=11/12) ----
  run1(stream, TD(0, 2, 512, Wt[0],96, tem,96,11,2048L*96,
                  xW,2048,256L*2048, nullptr,0,0, 11, 96));
  run2p(stream,
    TD(0, 32, 512, MTb,2048, xW,2048,7,256L*2048,
       eg0,128,4096L*128, nullptr,0,0, 7, 2048),
    TD(0, 16, 256, S0b,2048, xW+128*2048,2048,7,256L*2048,
       cat1,256,2048L*256, nullptr,0,0, 7, 2048));
  run1(stream, TD(0, 1, 512, Wt[4],128, eg0,128,12,4096L*128,
                  eg0p,4096,128L*4096, nullptr,0,0, 12, 128));
  run1(stream, TD(0, 32, 512, S1b,4096, eg0p,4096,7,128L*4096,
                  eg1nf,128,4096L*128, eg1fn,4096,128L*4096, 7, 4096));
  run2p(stream,
    TD(0, 16, 256, Mb,4096, eg1fn,4096,7,128L*4096,
       cat1+128,256,2048L*256, nullptr,0,0, 7, 4096),
    TD(0, 1, 512, Wt[5],128, eg1nf,128,12,4096L*128,
       eg1p,4096,128L*4096, nullptr,0,0, 12, 128));
  run2p(stream,
    TD(0, 1, 256, Wt[2],256, cat1,256,11,2048L*256,
       cp1,2048,128L*2048, nullptr,0,0, 11, 256),
    TD(0, 32, 512, S1b,4096, eg1p,4096,7,128L*4096,
       nullptr,0,0, eg2fn,4096,128L*4096, 7, 4096));
  run2p(stream,
    TD(0, 16, 256, S0b,2048, cp1,2048,7,128L*2048,
       cat2,256,2048L*256, nullptr,0,0, 7, 2048),
    TD(0, 16, 256, Mb,4096, eg2fn,4096,7,128L*4096,
       cat2+128,256,2048L*256, nullptr,0,0, 7, 4096));
  run1(stream, TD(0, 1, 256, Wt[3],256, cat2,256,11,2048L*256,
                  cp2,2048,128L*2048, nullptr,0,0, 11, 256));
  run1(stream, TD(0, 16, 256, S0b,2048, cp2,2048,7,128L*2048,
                  hop2,128,2048L*128, nullptr,0,0, 7, 2048));
  attention_k<128><<<dim3(512, 16), 256, 0, stream>>>(cat1,256, cat2,256, hop2,128, s1, feab);
  build_tem2<<<dim3(768, 16), 256, 0, stream>>>(x, hid, feab, tem);

  // g2 buffers (feab live at T4 lo):
  bf16* xW2     = (bf16*)T0;               // [z][128][2048]
  bf16* eg0_2   = (bf16*)T1;               // [z][4096][64]
  bf16* cat1_2  = (bf16*)T2;               // [z][2048][128]
  bf16* eg0p_2  = (bf16*)T3;               // [z][64][4096]
  bf16* eg1nf_2 = (bf16*)(T4 + 8388608);   // [z][4096][64]
  bf16* eg1fn_2 = (bf16*)T0;               // [z][64][4096]
  bf16* eg1p_2  = (bf16*)T3;               // [z][64][4096]
  bf16* cp1_2   = (bf16*)T1;               // [z][64][2048]
  bf16* eg2fn_2 = (bf16*)T0;               // [z][64][4096]
  bf16* cat2_2  = (bf16*)T3;               // [z][2048][128]
  bf16* cp2_2   = (bf16*)T1;               // [z][64][2048]
  bf16* hop2_2  = (bf16*)(T1 + 4194304);   // [z][2048][64]

  // ---- g2 (F = 64; agg zshC=6, proj zshC=11/12) ----
  run1(stream, TD(0, 1, 256, Wt[6],96, tem,96,11,2048L*96,
                  xW2,2048,128L*2048, nullptr,0,0, 11, 96));
  run2p(stream,
    TD(0, 32, 256, MTb,2048, xW2,2048,6,128L*2048,
       eg0_2,64,4096L*64, nullptr,0,0, 6, 2048),
    TD(0, 16, 128, S0b,2048, xW2+64*2048,2048,6,128L*2048,
       cat1_2,128,2048L*128, nullptr,0,0, 6, 2048));
  run1(stream, TD(1, 1, 512, Wt[10],64, eg0_2,64,12,4096L*64,
                  eg0p_2,4096,64L*4096, nullptr,0,0, 12, 64));
  run1(stream, TD(0, 32, 256, S1b,4096, eg0p_2,4096,6,64L*4096,
                  eg1nf_2,64,4096L*64, eg1fn_2,4096,64L*4096, 6, 4096));
  run2p(stream,
    TD(0, 16, 128, Mb,4096, eg1fn_2,4096,6,64L*4096,
       cat1_2+64,128,2048L*128, nullptr,0,0, 6, 4096),
    TD(1, 1, 512, Wt[11],64, eg1nf_2,64,12,4096L*64,
       eg1p_2,4096,64L*4096, nullptr,0,0, 12, 64));
  run2p(stream,
    TD(1, 1, 256, Wt[8],128, cat1_2,128,11,2048L*128,
       cp1_2,2048,64L*2048, nullptr,0,0, 11, 128),
    TD(0, 32, 256, S1b,4096, eg1p_2,4096,6,64L*4096,
       nullptr,0,0, eg2fn_2,4096,64L*4096, 6, 4096));
  run2p(stream,
    TD(0, 16, 128, S0b,2048, cp1_2,2048,6,64L*2048,
       cat2_2,128,2048L*128, nullptr,0,0, 6, 2048),
    TD(0, 16, 128, Mb,4096, eg2fn_2,4096,6,64L*4096,
       cat2_2+64,128,2048L*128, nullptr,0,0, 6, 4096));
  run1(stream, TD(1, 1, 256, Wt[9],128, cat2_2,128,11,2048L*128,
                  cp2_2,2048,64L*2048, nullptr,0,0, 11, 128));
  run1(stream, TD(0, 16, 128, S0b,2048, cp2_2,2048,6,64L*2048,
                  hop2_2,64,2048L*64, nullptr,0,0, 6, 2048));
  attention_k<64><<<dim3(512, 16), 256, 0, stream>>>(cat1_2,128, cat2_2,128, hop2_2,64, s2, ccb);

  gru_out<<<dim3(500, 16), 256, 0, stream>>>(feab, ccb, hid, (float*)d_out);
}

// Round 5
// 794.477 us; speedup vs baseline: 1.2604x; 1.2604x over previous
//
#include <hip/hip_runtime.h>
#include <stdint.h>

// ---------------------------------------------------------------------------
// BGCGRU on MI355X: all heavy ops as bf16 MFMA NT-GEMMs (fp32 accumulate).
//   aggregation  C[m,f] = sum_n S[m,n]   * X[f,n]   (X spatial-contiguous)
//   projection   C[c,n] = sum_f W^T[c,f] * Y[n,f]   (Y feature-contiguous)
// Round 5: revert to the proven round-3 2-phase double-buffer (one
// __syncthreads per K-iter), but BK 32->64: 2x MFMA per barrier drain,
// half the drains. K=96 ops padded to 128 so all K are multiples of 64.
// z folded into N (pow2 decode in epilogue). XOR swizzle re-derived for
// 128B rows: LDS[row][seg] = global[row][seg ^ (row&7)], seg = 16B unit.
// ---------------------------------------------------------------------------

typedef __bf16 bf16;
typedef float  f32x4  __attribute__((ext_vector_type(4)));
typedef __bf16 bf16x8 __attribute__((ext_vector_type(8)));
typedef __bf16 bf16x4v __attribute__((ext_vector_type(4)));

#define DEVI __device__ __forceinline__

DEVI void gload16(const bf16* g, bf16* l) {
  __builtin_amdgcn_global_load_lds(
      (const __attribute__((address_space(1))) void*)g,
      (__attribute__((address_space(3))) void*)l, 16, 0, 0);
}

struct GemmArgs {
  const bf16* A; const bf16* B;
  bf16* Cn;   // normal write:  [z] row-major [m][col], nullable
  bf16* Ct;   // transposed:    [z] row-major [col][m], nullable
  int lda, ldb, ldcn, ldct, K, zshB, zshC;
  long sB, sCn, sCt;   // per-z element strides
};

struct TaskDesc { GemmArgs g; int kind, gx, blk0, nblk; };
struct MultiArgs { TaskDesc t[2]; int nt; };

// 2-phase double-buffered NT GEMM, BK=64. 4 waves (2x2), 16x16x32 bf16 MFMA.
// One __syncthreads per K-iter; stage(t+1) issued before compute(t).
template<int BM, int BN>
DEVI void gemm_body(const GemmArgs& g, int bx, int by, bf16* smem) {
  constexpr int BK  = 64;
  constexpr int ASZ = BM * BK, BSZ = BN * BK;
  bf16* Abuf = smem;
  bf16* Bbuf = smem + 2 * ASZ;
  const int tid  = threadIdx.x;
  const int wave = tid >> 6;
  const int lane = tid & 63;
  const int wm = (wave >> 1) * (BM / 2);
  const int wn = (wave & 1) * (BN / 2);
  constexpr int FM = BM / 32;
  constexpr int FN = BN / 32;

  // Staging: per round, 256 thr x 16B = 32 rows of 128B. row=(tid>>3), seg=tid&7.
  // LDS[row][seg] holds global[row][seg ^ (row&7)]  (involution).
  const int sseg = (((tid & 7) ^ ((tid >> 3) & 7))) * 8;  // global seg, elems
  const int l15  = lane & 15;
  const int lq   = lane >> 4;                              // 0..3

  // Loop-invariant per-thread global row pointers (z-fold decode for B).
  const bf16* arow[BM / 32];
  #pragma unroll
  for (int c = 0; c < BM / 32; ++c)
    arow[c] = g.A + (long)(bx * BM + c * 32 + (tid >> 3)) * g.lda + sseg;
  const bf16* brow[BN / 32];
  const int maskB = (1 << g.zshB) - 1;
  #pragma unroll
  for (int c = 0; c < BN / 32; ++c) {
    const int nb = by * BN + c * 32 + (tid >> 3);
    brow[c] = g.B + (long)(nb >> g.zshB) * g.sB + (long)(nb & maskB) * g.ldb + sseg;
  }

  f32x4 acc[FM][FN] = {};

  auto stage = [&](int buf, int kt) {
    #pragma unroll
    for (int c = 0; c < BM / 32; ++c)
      gload16(arow[c] + kt, &Abuf[buf * ASZ + c * 2048 + tid * 8]);
    #pragma unroll
    for (int c = 0; c < BN / 32; ++c)
      gload16(brow[c] + kt, &Bbuf[buf * BSZ + c * 2048 + tid * 8]);
  };
  auto compute = [&](int cb) {
    #pragma unroll
    for (int kk = 0; kk < 2; ++kk) {
      bf16x8 af[FM], bfr[FN];
      #pragma unroll
      for (int i = 0; i < FM; ++i) {
        const int R = wm + i * 16 + l15;
        af[i] = *(const bf16x8*)
            &Abuf[cb * ASZ + R * 64 + ((kk * 4 + lq) ^ (l15 & 7)) * 8];
      }
      #pragma unroll
      for (int j = 0; j < FN; ++j) {
        const int R = wn + j * 16 + l15;
        bfr[j] = *(const bf16x8*)
            &Bbuf[cb * BSZ + R * 64 + ((kk * 4 + lq) ^ (l15 & 7)) * 8];
      }
      #pragma unroll
      for (int i = 0; i < FM; ++i)
        #pragma unroll
        for (int j = 0; j < FN; ++j)
          acc[i][j] = __builtin_amdgcn_mfma_f32_16x16x32_bf16(af[i], bfr[j],
                                                              acc[i][j], 0, 0, 0);
    }
  };

  const int nt = g.K / BK;
  stage(0, 0);
  __syncthreads();
  int cur = 0;
  for (int t = 0; t < nt; ++t) {
    if (t + 1 < nt) stage(cur ^ 1, (t + 1) * BK);
    compute(cur);
    __syncthreads();
    cur ^= 1;
  }

  // Epilogue. C/D layout (m89-verified): col = lane&15, row = (lane>>4)*4+r.
  const int gm0 = bx * BM + wm;
  const int gn0 = by * BN + wn;
  const int rowq = lq * 4;
  const int maskC = (1 << g.zshC) - 1;
  if (g.Cn) {
    #pragma unroll
    for (int i = 0; i < FM; ++i)
      #pragma unroll
      for (int j = 0; j < FN; ++j) {
        const int m0 = gm0 + i * 16 + rowq;
        const int ng = gn0 + j * 16 + l15;
        bf16* Cz = g.Cn + (long)(ng >> g.zshC) * g.sCn + (ng & maskC);
        #pragma unroll
        for (int r = 0; r < 4; ++r)
          Cz[(long)(m0 + r) * g.ldcn] = (bf16)acc[i][j][r];
      }
  }
  if (g.Ct) {
    #pragma unroll
    for (int i = 0; i < FM; ++i)
      #pragma unroll
      for (int j = 0; j < FN; ++j) {
        const int m0 = gm0 + i * 16 + rowq;
        const int ng = gn0 + j * 16 + l15;
        bf16x4v v = { (bf16)acc[i][j][0], (bf16)acc[i][j][1],
                      (bf16)acc[i][j][2], (bf16)acc[i][j][3] };
        *(bf16x4v*)(g.Ct + (long)(ng >> g.zshC) * g.sCt
                    + (long)(ng & maskC) * g.ldct + m0) = v;
      }
  }
}

__global__ __launch_bounds__(256) void gemm_multi(MultiArgs mu) {
  __shared__ bf16 smem[32768];    // 64 KB: 2 dbuf x (A+B), kind0 size
  const int b = blockIdx.x;
  const int ti = (mu.nt > 1 && b >= mu.t[1].blk0) ? 1 : 0;
  const TaskDesc t = mu.t[ti];
  const int local = b - t.blk0;
  const int bx = local % t.gx;
  const int by = local / t.gx;
  if (t.kind == 0) gemm_body<128, 128>(t.g, bx, by, smem);
  else             gemm_body< 64, 128>(t.g, bx, by, smem);
}

// ---------------- prep / elementwise kernels -------------------------------

__global__ void cvt_pad(const float* in, int R, int C, bf16* out, int Cp) {
  const int r = blockIdx.y;
  const int c = blockIdx.x * blockDim.x + threadIdx.x;
  float v = (r < R && c < C) ? in[(long)r * C + c] : 0.f;
  out[(long)r * Cp + c] = (bf16)v;
}

__global__ void cvt_transpose(const float* in, int R, int C, bf16* out, int ldo) {
  __shared__ float t[64][65];
  const int n0 = blockIdx.x * 64;
  const int e0 = blockIdx.y * 64;
  const int tx = threadIdx.x, ty = threadIdx.y;
  for (int i = ty; i < 64; i += 4) {
    int r = n0 + i, c = e0 + tx;
    t[i][tx] = (r < R && c < C) ? in[(long)r * C + c] : 0.f;
  }
  __syncthreads();
  for (int i = ty; i < 64; i += 4)
    out[(long)(e0 + i) * ldo + n0 + tx] = (bf16)t[tx][i];
}

struct WPrep { const float* W; bf16* WT; int Fin, Fout, ldt; };
struct WAll {
  WPrep w[12];
  const float* aw1; const float* al1; float* s1;
  const float* aw2; const float* al2; float* s2;
};
__global__ void prep_weights(WAll a) {
  const int b = blockIdx.x;
  if (b < 12) {
    WPrep w = a.w[b];
    for (int i = threadIdx.x; i < w.Fout * w.ldt; i += blockDim.x) {
      int c = i / w.ldt, f = i % w.ldt;
      float v = (f < w.Fin) ? w.W[(long)f * w.Fout + c] : 0.f;
      w.WT[i] = (bf16)v;
    }
  } else if (b == 12) {
    for (int f = threadIdx.x; f < 128; f += blockDim.x) {
      float s = 0.f;
      for (int w = 0; w < 128; ++w) s += a.aw1[w * 128 + f] * a.al1[w];
      a.s1[f] = s;
    }
  } else {
    for (int f = threadIdx.x; f < 64; f += blockDim.x) {
      float s = 0.f;
      for (int w = 0; w < 64; ++w) s += a.aw2[w * 64 + f] * a.al2[w];
      a.s2[f] = s;
    }
  }
}

// tem stride 128 (K padded 96->128).
__global__ void build_tem1(const float* x, const float* h, bf16* tem) {
  const int b = blockIdx.y;
  const int i = blockIdx.x * blockDim.x + threadIdx.x;  // < 2048*128
  const int f = i & 127, n = i >> 7;
  float v = 0.f;
  if (n < 2000 && f < 66) {
    if (f < 2) v = x[(long)b * 4000 + n * 2 + f];
    else       v = h[(long)b * 128000 + (long)n * 64 + (f - 2)];
  }
  tem[((long)b * 2048 + n) * 128 + f] = (bf16)v;
}

__global__ void build_tem2(const float* x, const float* h, const bf16* fea,
                           bf16* tem) {
  const int b = blockIdx.y;
  const int i = blockIdx.x * blockDim.x + threadIdx.x;
  const int f = i & 127, n = i >> 7;
  float v = 0.f;
  if (n < 2000 && f < 66) {
    if (f < 2) v = x[(long)b * 4000 + n * 2 + f];
    else {
      int co = f - 2;
      float r = (float)fea[((long)b * 2048 + n) * 128 + 64 + co];
      v = (1.f / (1.f + expf(-r))) * h[(long)b * 128000 + (long)n * 64 + co];
    }
  }
  tem[((long)b * 2048 + n) * 128 + f] = (bf16)v;
}

template<int F>
__global__ void attention_k(const bf16* hop0, int ld0, const bf16* hop1, int ld1,
                            const bf16* hop2, int ld2, const float* s, bf16* fea) {
  const int nloc = blockIdx.x * 4 + (threadIdx.x >> 6);
  const int b = blockIdx.y;
  const int lane = threadIdx.x & 63;
  const long bn = (long)b * 2048 + nloc;
  constexpr int NF = F / 64;
  float h0[NF], h1[NF], h2[NF];
  float d0 = 0.f, d1 = 0.f, d2 = 0.f;
  #pragma unroll
  for (int q = 0; q < NF; ++q) {
    int f = lane + q * 64;
    h0[q] = (float)hop0[bn * ld0 + f];
    h1[q] = (float)hop1[bn * ld1 + f];
    h2[q] = (float)hop2[bn * ld2 + f];
    float sv = s[f];
    d0 += h0[q] * sv; d1 += h1[q] * sv; d2 += h2[q] * sv;
  }
  #pragma unroll
  for (int o = 32; o; o >>= 1) {
    d0 += __shfl_xor(d0, o); d1 += __shfl_xor(d1, o); d2 += __shfl_xor(d2, o);
  }
  float mx = fmaxf(d0, fmaxf(d1, d2));
  float e0 = expf(d0 - mx), e1 = expf(d1 - mx), e2 = expf(d2 - mx);
  float inv = 1.f / (e0 + e1 + e2);
  e0 *= inv; e1 *= inv; e2 *= inv;
  #pragma unroll
  for (int q = 0; q < NF; ++q) {
    int f = lane + q * 64;
    fea[bn * F + f] = (bf16)(e0 * h0[q] + e1 * h1[q] + e2 * h2[q]);
  }
}

__global__ void gru_out(const bf16* fea, const bf16* cc, const float* h,
                        float* out) {
  const int b = blockIdx.y;
  const int i = blockIdx.x * blockDim.x + threadIdx.x;
  const int co = i & 63, n = i >> 6;
  float z  = (float)fea[((long)b * 2048 + n) * 128 + co];
  float c  = (float)cc [((long)b * 2048 + n) * 64 + co];
  float hv = h[(long)b * 128000 + i];
  float zs = 1.f / (1.f + expf(-z));
  out[(long)b * 128000 + i] = zs * hv + (1.f - zs) * tanhf(c);
}

__global__ void ws_diag(float* out, int n, float v) {
  int i = blockIdx.x * blockDim.x + threadIdx.x;
  if (i < n) out[i] = v;
}

// ---------------------------------------------------------------------------

static TaskDesc TD(int kind, int gx, int nblk,
                   const bf16* A, int lda,
                   const bf16* B, int ldb, int zshB, long sB,
                   bf16* Cn, int ldcn, long sCn,
                   bf16* Ct, int ldct, long sCt, int zshC, int K) {
  TaskDesc t;
  t.g = GemmArgs{A, B, Cn, Ct, lda, ldb, ldcn, ldct, K, zshB, zshC, sB, sCn, sCt};
  t.kind = kind; t.gx = gx; t.blk0 = 0; t.nblk = nblk;
  return t;
}
static void run1(hipStream_t st, TaskDesc a) {
  MultiArgs m; m.t[0] = a; m.t[0].blk0 = 0; m.nt = 1;
  gemm_multi<<<a.nblk, 256, 0, st>>>(m);
}
static void run2p(hipStream_t st, TaskDesc a, TaskDesc b) {
  MultiArgs m; m.t[0] = a; m.t[0].blk0 = 0;
  m.t[1] = b; m.t[1].blk0 = a.nblk; m.nt = 2;
  gemm_multi<<<a.nblk + b.nblk, 256, 0, st>>>(m);
}

extern "C" void kernel_launch(void* const* d_in, const int* in_sizes, int n_in,
                              void* d_out, int out_size, void* d_ws, size_t ws_size,
                              hipStream_t stream) {
  const float* x    = (const float*)d_in[0];
  const float* hid  = (const float*)d_in[1];
  const float* S0   = (const float*)d_in[2];
  const float* S1   = (const float*)d_in[3];
  const float* M    = (const float*)d_in[4];

  char* base = (char*)d_ws;
  size_t off = 0;
  auto alloc = [&](size_t bytes) -> void* {
    void* r = base + off;
    off += (bytes + 255) & ~(size_t)255;
    return r;
  };

  bf16* S0b = (bf16*)alloc(2048ull * 2048 * 2);
  bf16* S1b = (bf16*)alloc(4096ull * 4096 * 2);
  bf16* Mb  = (bf16*)alloc(2048ull * 4096 * 2);
  bf16* MTb = (bf16*)alloc(4096ull * 2048 * 2);
  bf16* tem = (bf16*)alloc(16ull * 2048 * 128 * 2);   // stride 128
  bf16* ccb = (bf16*)alloc(16ull * 2048 * 64 * 2);

  // K-padded transposed weights (66->128 pad for 0,1,6,7)
  static const int wd[12][3] = {
    {66,128,128},{66,128,128},{256,128,256},{256,128,256},{128,128,128},{128,128,128},
    {66, 64,128},{66, 64,128},{128, 64,128},{128, 64,128},{ 64, 64, 64},{ 64, 64, 64}};
  static const int wsrc[12] = {5,6,7,8,9,10, 13,14,15,16,17,18};
  bf16* Wt[12];
  for (int i = 0; i < 12; ++i) Wt[i] = (bf16*)alloc((size_t)wd[i][1] * wd[i][2] * 2);
  float* s1 = (float*)alloc(128 * 4);
  float* s2 = (float*)alloc(64 * 4);

  const size_t SLOT = 16ull * 4096 * 128 * 2;  // 16 MB
  char* T0 = (char*)alloc(SLOT);
  char* T1 = (char*)alloc(SLOT);
  char* T2 = (char*)alloc(SLOT);
  char* T3 = (char*)alloc(SLOT);
  char* T4 = (char*)alloc(SLOT);

  if (off > ws_size) {
    ws_diag<<<4, 256, 0, stream>>>((float*)d_out, 1024, (float)(ws_size >> 20));
    return;
  }

  // g1 buffers (liveness identical to round 3):
  bf16* xW    = (bf16*)T0;               // [z][256][2048]
  bf16* eg0   = (bf16*)T1;               // [z][4096][128]
  bf16* cat1  = (bf16*)T2;               // [z][2048][256]
  bf16* eg0p  = (bf16*)T3;               // [z][128][4096]
  bf16* eg1nf = (bf16*)T4;               // [z][4096][128]
  bf16* eg1fn = (bf16*)T0;               // [z][128][4096]
  bf16* eg1p  = (bf16*)T3;               // [z][128][4096]
  bf16* cp1   = (bf16*)T1;               // [z][128][2048]
  bf16* eg2fn = (bf16*)T0;               // [z][128][4096]
  bf16* cat2  = (bf16*)T3;               // [z][2048][256]
  bf16* cp2   = (bf16*)T1;               // [z][128][2048]
  bf16* hop2  = (bf16*)(T1 + 8388608);   // [z][2048][128]
  bf16* feab  = (bf16*)T4;               // [z][2048][128]

  // ---- prep ----
  cvt_pad<<<dim3(8, 2048), 256, 0, stream>>>(S0, 2000, 2000, S0b, 2048);
  cvt_pad<<<dim3(16, 4096), 256, 0, stream>>>(S1, 4000, 4000, S1b, 4096);
  cvt_pad<<<dim3(16, 2048), 256, 0, stream>>>(M, 2000, 4000, Mb, 4096);
  cvt_transpose<<<dim3(32, 64), dim3(64, 4), 0, stream>>>(M, 2000, 4000, MTb, 2048);
  WAll wa;
  for (int i = 0; i < 12; ++i)
    wa.w[i] = WPrep{(const float*)d_in[wsrc[i]], Wt[i], wd[i][0], wd[i][1], wd[i][2]};
  wa.aw1 = (const float*)d_in[11]; wa.al1 = (const float*)d_in[12]; wa.s1 = s1;
  wa.aw2 = (const float*)d_in[19]; wa.al2 = (const float*)d_in[20]; wa.s2 = s2;
  prep_weights<<<14, 256, 0, stream>>>(wa);
  build_tem1<<<dim3(1024, 16), 256, 0, stream>>>(x, hid, tem);

  // ---- g1 (F = 128; agg zshC=7, proj zshC=11/12) ----
  run1(stream, TD(0, 2, 512, Wt[0],128, tem,128,11,2048L*128,
                  xW,2048,256L*2048, nullptr,0,0, 11, 128));
  run2p(stream,
    TD(0, 32, 512, MTb,2048, xW,2048,7,256L*2048,
       eg0,128,4096L*128, nullptr,0,0, 7, 2048),
    TD(0, 16, 256, S0b,2048, xW+128*2048,2048,7,256L*2048,
       cat1,256,2048L*256, nullptr,0,0, 7, 2048));
  run1(stream, TD(0, 1, 512, Wt[4],128, eg0,128,12,4096L*128,
                  eg0p,4096,128L*4096, nullptr,0,0, 12, 128));
  run1(stream, TD(0, 32, 512, S1b,4096, eg0p,4096,7,128L*4096,
                  eg1nf,128,4096L*128, eg1fn,4096,128L*4096, 7, 4096));
  run2p(stream,
    TD(0, 16, 256, Mb,4096, eg1fn,4096,7,128L*4096,
       cat1+128,256,2048L*256, nullptr,0,0, 7, 4096),
    TD(0, 1, 512, Wt[5],128, eg1nf,128,12,4096L*128,
       eg1p,4096,128L*4096, nullptr,0,0, 12, 128));
  run2p(stream,
    TD(0, 1, 256, Wt[2],256, cat1,256,11,2048L*256,
       cp1,2048,128L*2048, nullptr,0,0, 11, 256),
    TD(0, 32, 512, S1b,4096, eg1p,4096,7,128L*4096,
       nullptr,0,0, eg2fn,4096,128L*4096, 7, 4096));
  run2p(stream,
    TD(0, 16, 256, S0b,2048, cp1,2048,7,128L*2048,
       cat2,256,2048L*256, nullptr,0,0, 7, 2048),
    TD(0, 16, 256, Mb,4096, eg2fn,4096,7,128L*4096,
       cat2+128,256,2048L*256, nullptr,0,0, 7, 4096));
  run1(stream, TD(0, 1, 256, Wt[3],256, cat2,256,11,2048L*256,
                  cp2,2048,128L*2048, nullptr,0,0, 11, 256));
  run1(stream, TD(0, 16, 256, S0b,2048, cp2,2048,7,128L*2048,
                  hop2,128,2048L*128, nullptr,0,0, 7, 2048));
  attention_k<128><<<dim3(512, 16), 256, 0, stream>>>(cat1,256, cat2,256, hop2,128, s1, feab);
  build_tem2<<<dim3(1024, 16), 256, 0, stream>>>(x, hid, feab, tem);

  // g2 buffers (feab live at T4 lo):
  bf16* xW2     = (bf16*)T0;               // [z][128][2048]
  bf16* eg0_2   = (bf16*)T1;               // [z][4096][64]
  bf16* cat1_2  = (bf16*)T2;               // [z][2048][128]
  bf16* eg0p_2  = (bf16*)T3;               // [z][64][4096]
  bf16* eg1nf_2 = (bf16*)(T4 + 8388608);   // [z][4096][64]
  bf16* eg1fn_2 = (bf16*)T0;               // [z][64][4096]
  bf16* eg1p_2  = (bf16*)T3;               // [z][64][4096]
  bf16* cp1_2   = (bf16*)T1;               // [z][64][2048]
  bf16* eg2fn_2 = (bf16*)T0;               // [z][64][4096]
  bf16* cat2_2  = (bf16*)T3;               // [z][2048][128]
  bf16* cp2_2   = (bf16*)T1;               // [z][64][2048]
  bf16* hop2_2  = (bf16*)(T1 + 4194304);   // [z][2048][64]

  // ---- g2 (F = 64; agg zshC=6, proj zshC=11/12) ----
  run1(stream, TD(0, 1, 256, Wt[6],128, tem,128,11,2048L*128,
                  xW2,2048,128L*2048, nullptr,0,0, 11, 128));
  run2p(stream,
    TD(0, 32, 256, MTb,2048, xW2,2048,6,128L*2048,
       eg0_2,64,4096L*64, nullptr,0,0, 6, 2048),
    TD(0, 16, 128, S0b,2048, xW2+64*2048,2048,6,128L*2048,
       cat1_2,128,2048L*128, nullptr,0,0, 6, 2048));
  run1(stream, TD(1, 1, 512, Wt[10],64, eg0_2,64,12,4096L*64,
                  eg0p_2,4096,64L*4096, nullptr,0,0, 12, 64));
  run1(stream, TD(0, 32, 256, S1b,4096, eg0p_2,4096,6,64L*4096,
                  eg1nf_2,64,4096L*64, eg1fn_2,4096,64L*4096, 6, 4096));
  run2p(stream,
    TD(0, 16, 128, Mb,4096, eg1fn_2,4096,6,64L*4096,
       cat1_2+64,128,2048L*128, nullptr,0,0, 6, 4096),
    TD(1, 1, 512, Wt[11],64, eg1nf_2,64,12,4096L*64,
       eg1p_2,4096,64L*4096, nullptr,0,0, 12, 64));
  run2p(stream,
    TD(1, 1, 256, Wt[8],128, cat1_2,128,11,2048L*128,
       cp1_2,2048,64L*2048, nullptr,0,0, 11, 128),
    TD(0, 32, 256, S1b,4096, eg1p_2,4096,6,64L*4096,
       nullptr,0,0, eg2fn_2,4096,64L*4096, 6, 4096));
  run2p(stream,
    TD(0, 16, 128, S0b,2048, cp1_2,2048,6,64L*2048,
       cat2_2,128,2048L*128, nullptr,0,0, 6, 2048),
    TD(0, 16, 128, Mb,4096, eg2fn_2,4096,6,64L*4096,
       cat2_2+64,128,2048L*128, nullptr,0,0, 6, 4096));
  run1(stream, TD(1, 1, 256, Wt[9],128, cat2_2,128,11,2048L*128,
                  cp2_2,2048,64L*2048, nullptr,0,0, 11, 128));
  run1(stream, TD(0, 16, 128, S0b,2048, cp2_2,2048,6,64L*2048,
                  hop2_2,64,2048L*64, nullptr,0,0, 6, 2048));
  attention_k<64><<<dim3(512, 16), 256, 0, stream>>>(cat1_2,128, cat2_2,128, hop2_2,64, s2, ccb);

  gru_out<<<dim3(500, 16), 256, 0, stream>>>(feab, ccb, hid, (float*)d_out);
}

// Round 6
// 779.229 us; speedup vs baseline: 1.2850x; 1.0196x over previous
//
#include <hip/hip_runtime.h>
#include <stdint.h>

// ---------------------------------------------------------------------------
// BGCGRU on MI355X: all heavy ops as bf16 MFMA NT-GEMMs (fp32 accumulate).
//   aggregation  C[m,f] = sum_n S[m,n]   * X[f,n]   (X spatial-contiguous)
//   projection   C[c,n] = sum_f W^T[c,f] * Y[n,f]   (Y feature-contiguous)
// Round 6: round-5 GEMM core unchanged (2-phase dbuf, BK=64, XOR swizzle).
// New: XCD M-stripe block swizzle (each XCD owns a contiguous bx-stripe x
// all by -> A-panel stays in its private L2; B-panel shared by co-resident
// blocks), longest-task-first in merged launches, cvt_pad x3 fused,
// attention1+build_tem2 fused (shfl r-gate), attention2+gru_out fused.
// ---------------------------------------------------------------------------

typedef __bf16 bf16;
typedef float  f32x4  __attribute__((ext_vector_type(4)));
typedef __bf16 bf16x8 __attribute__((ext_vector_type(8)));
typedef __bf16 bf16x4v __attribute__((ext_vector_type(4)));

#define DEVI __device__ __forceinline__

DEVI void gload16(const bf16* g, bf16* l) {
  __builtin_amdgcn_global_load_lds(
      (const __attribute__((address_space(1))) void*)g,
      (__attribute__((address_space(3))) void*)l, 16, 0, 0);
}

struct GemmArgs {
  const bf16* A; const bf16* B;
  bf16* Cn;   // normal write:  [z] row-major [m][col], nullable
  bf16* Ct;   // transposed:    [z] row-major [col][m], nullable
  int lda, ldb, ldcn, ldct, K, zshB, zshC;
  long sB, sCn, sCt;   // per-z element strides
};

struct TaskDesc { GemmArgs g; int kind, gx, blk0, nblk; };
struct MultiArgs { TaskDesc t[2]; int nt; };

// 2-phase double-buffered NT GEMM, BK=64. 4 waves (2x2), 16x16x32 bf16 MFMA.
// One __syncthreads per K-iter; stage(t+1) issued before compute(t).
template<int BM, int BN>
DEVI void gemm_body(const GemmArgs& g, int bx, int by, bf16* smem) {
  constexpr int BK  = 64;
  constexpr int ASZ = BM * BK, BSZ = BN * BK;
  bf16* Abuf = smem;
  bf16* Bbuf = smem + 2 * ASZ;
  const int tid  = threadIdx.x;
  const int wave = tid >> 6;
  const int lane = tid & 63;
  const int wm = (wave >> 1) * (BM / 2);
  const int wn = (wave & 1) * (BN / 2);
  constexpr int FM = BM / 32;
  constexpr int FN = BN / 32;

  // Staging: per round, 256 thr x 16B = 32 rows of 128B. row=(tid>>3), seg=tid&7.
  // LDS[row][seg] holds global[row][seg ^ (row&7)]  (involution).
  const int sseg = (((tid & 7) ^ ((tid >> 3) & 7))) * 8;  // global seg, elems
  const int l15  = lane & 15;
  const int lq   = lane >> 4;                              // 0..3

  // Loop-invariant per-thread global row pointers (z-fold decode for B).
  const bf16* arow[BM / 32];
  #pragma unroll
  for (int c = 0; c < BM / 32; ++c)
    arow[c] = g.A + (long)(bx * BM + c * 32 + (tid >> 3)) * g.lda + sseg;
  const bf16* brow[BN / 32];
  const int maskB = (1 << g.zshB) - 1;
  #pragma unroll
  for (int c = 0; c < BN / 32; ++c) {
    const int nb = by * BN + c * 32 + (tid >> 3);
    brow[c] = g.B + (long)(nb >> g.zshB) * g.sB + (long)(nb & maskB) * g.ldb + sseg;
  }

  f32x4 acc[FM][FN] = {};

  auto stage = [&](int buf, int kt) {
    #pragma unroll
    for (int c = 0; c < BM / 32; ++c)
      gload16(arow[c] + kt, &Abuf[buf * ASZ + c * 2048 + tid * 8]);
    #pragma unroll
    for (int c = 0; c < BN / 32; ++c)
      gload16(brow[c] + kt, &Bbuf[buf * BSZ + c * 2048 + tid * 8]);
  };
  auto compute = [&](int cb) {
    #pragma unroll
    for (int kk = 0; kk < 2; ++kk) {
      bf16x8 af[FM], bfr[FN];
      #pragma unroll
      for (int i = 0; i < FM; ++i) {
        const int R = wm + i * 16 + l15;
        af[i] = *(const bf16x8*)
            &Abuf[cb * ASZ + R * 64 + ((kk * 4 + lq) ^ (l15 & 7)) * 8];
      }
      #pragma unroll
      for (int j = 0; j < FN; ++j) {
        const int R = wn + j * 16 + l15;
        bfr[j] = *(const bf16x8*)
            &Bbuf[cb * BSZ + R * 64 + ((kk * 4 + lq) ^ (l15 & 7)) * 8];
      }
      #pragma unroll
      for (int i = 0; i < FM; ++i)
        #pragma unroll
        for (int j = 0; j < FN; ++j)
          acc[i][j] = __builtin_amdgcn_mfma_f32_16x16x32_bf16(af[i], bfr[j],
                                                              acc[i][j], 0, 0, 0);
    }
  };

  const int nt = g.K / BK;
  stage(0, 0);
  __syncthreads();
  int cur = 0;
  for (int t = 0; t < nt; ++t) {
    if (t + 1 < nt) stage(cur ^ 1, (t + 1) * BK);
    compute(cur);
    __syncthreads();
    cur ^= 1;
  }

  // Epilogue. C/D layout (m89-verified): col = lane&15, row = (lane>>4)*4+r.
  const int gm0 = bx * BM + wm;
  const int gn0 = by * BN + wn;
  const int rowq = lq * 4;
  const int maskC = (1 << g.zshC) - 1;
  if (g.Cn) {
    #pragma unroll
    for (int i = 0; i < FM; ++i)
      #pragma unroll
      for (int j = 0; j < FN; ++j) {
        const int m0 = gm0 + i * 16 + rowq;
        const int ng = gn0 + j * 16 + l15;
        bf16* Cz = g.Cn + (long)(ng >> g.zshC) * g.sCn + (ng & maskC);
        #pragma unroll
        for (int r = 0; r < 4; ++r)
          Cz[(long)(m0 + r) * g.ldcn] = (bf16)acc[i][j][r];
      }
  }
  if (g.Ct) {
    #pragma unroll
    for (int i = 0; i < FM; ++i)
      #pragma unroll
      for (int j = 0; j < FN; ++j) {
        const int m0 = gm0 + i * 16 + rowq;
        const int ng = gn0 + j * 16 + l15;
        bf16x4v v = { (bf16)acc[i][j][0], (bf16)acc[i][j][1],
                      (bf16)acc[i][j][2], (bf16)acc[i][j][3] };
        *(bf16x4v*)(g.Ct + (long)(ng >> g.zshC) * g.sCt
                    + (long)(ng & maskC) * g.ldct + m0) = v;
      }
  }
}

__global__ __launch_bounds__(256) void gemm_multi(MultiArgs mu) {
  __shared__ bf16 smem[32768];    // 64 KB: 2 dbuf x (A+B), kind0 size
  const int b = blockIdx.x;
  const int ti = (mu.nt > 1 && b >= mu.t[1].blk0) ? 1 : 0;
  const TaskDesc t = mu.t[ti];
  const int local = b - t.blk0;
  int bx, by;
  if ((t.gx & 7) == 0) {
    // XCD M-stripe swizzle: blocks with equal (local&7) land on one XCD
    // (HW round-robin; blk0 % 8 == 0). Give each XCD a contiguous bx-stripe
    // of gx/8 columns across ALL by: A-stripe stays in its private L2, and
    // consecutive idx share by (B-panel co-residency).
    const int xcd = local & 7;
    const int idx = local >> 3;
    const int sub = t.gx >> 3;
    bx = xcd * sub + idx % sub;
    by = idx / sub;
  } else {
    bx = local % t.gx;
    by = local / t.gx;
  }
  if (t.kind == 0) gemm_body<128, 128>(t.g, bx, by, smem);
  else             gemm_body< 64, 128>(t.g, bx, by, smem);
}

// ---------------- prep / elementwise kernels -------------------------------

// All three support pads in one launch. grid (16, 8192).
__global__ void cvt_pad3(const float* S0, const float* S1, const float* M,
                         bf16* S0b, bf16* S1b, bf16* Mb) {
  const int y = blockIdx.y;
  const int c = blockIdx.x * blockDim.x + threadIdx.x;
  if (y < 2048) {
    if (c < 2048)
      S0b[(long)y * 2048 + c] =
          (bf16)((y < 2000 && c < 2000) ? S0[(long)y * 2000 + c] : 0.f);
  } else if (y < 6144) {
    const int r = y - 2048;
    S1b[(long)r * 4096 + c] =
        (bf16)((r < 4000 && c < 4000) ? S1[(long)r * 4000 + c] : 0.f);
  } else {
    const int r = y - 6144;
    Mb[(long)r * 4096 + c] =
        (bf16)((r < 2000 && c < 4000) ? M[(long)r * 4000 + c] : 0.f);
  }
}

__global__ void cvt_transpose(const float* in, int R, int C, bf16* out, int ldo) {
  __shared__ float t[64][65];
  const int n0 = blockIdx.x * 64;
  const int e0 = blockIdx.y * 64;
  const int tx = threadIdx.x, ty = threadIdx.y;
  for (int i = ty; i < 64; i += 4) {
    int r = n0 + i, c = e0 + tx;
    t[i][tx] = (r < R && c < C) ? in[(long)r * C + c] : 0.f;
  }
  __syncthreads();
  for (int i = ty; i < 64; i += 4)
    out[(long)(e0 + i) * ldo + n0 + tx] = (bf16)t[tx][i];
}

struct WPrep { const float* W; bf16* WT; int Fin, Fout, ldt; };
struct WAll {
  WPrep w[12];
  const float* aw1; const float* al1; float* s1;
  const float* aw2; const float* al2; float* s2;
};
__global__ void prep_weights(WAll a) {
  const int b = blockIdx.x;
  if (b < 12) {
    WPrep w = a.w[b];
    for (int i = threadIdx.x; i < w.Fout * w.ldt; i += blockDim.x) {
      int c = i / w.ldt, f = i % w.ldt;
      float v = (f < w.Fin) ? w.W[(long)f * w.Fout + c] : 0.f;
      w.WT[i] = (bf16)v;
    }
  } else if (b == 12) {
    for (int f = threadIdx.x; f < 128; f += blockDim.x) {
      float s = 0.f;
      for (int w = 0; w < 128; ++w) s += a.aw1[w * 128 + f] * a.al1[w];
      a.s1[f] = s;
    }
  } else {
    for (int f = threadIdx.x; f < 64; f += blockDim.x) {
      float s = 0.f;
      for (int w = 0; w < 64; ++w) s += a.aw2[w * 64 + f] * a.al2[w];
      a.s2[f] = s;
    }
  }
}

// tem stride 128 (K padded 96->128).
__global__ void build_tem1(const float* x, const float* h, bf16* tem) {
  const int b = blockIdx.y;
  const int i = blockIdx.x * blockDim.x + threadIdx.x;  // < 2048*128
  const int f = i & 127, n = i >> 7;
  float v = 0.f;
  if (n < 2000 && f < 66) {
    if (f < 2) v = x[(long)b * 4000 + n * 2 + f];
    else       v = h[(long)b * 128000 + (long)n * 64 + (f - 2)];
  }
  tem[((long)b * 2048 + n) * 128 + f] = (bf16)v;
}

// g1 attention (F=128) fused with build_tem2. One wave per (b,n).
// Writes fea z-half (64) to fea64 and the full tem2 row (128, padded).
__global__ void attention_fuse(const bf16* hop0, const bf16* hop1,
                               const bf16* hop2, const float* s,
                               const float* x, const float* h,
                               bf16* fea64, bf16* tem) {
  const int nloc = blockIdx.x * 4 + (threadIdx.x >> 6);
  const int b = blockIdx.y;
  const int lane = threadIdx.x & 63;
  const long bn = (long)b * 2048 + nloc;
  float h0[2], h1[2], h2[2];
  float d0 = 0.f, d1 = 0.f, d2 = 0.f;
  #pragma unroll
  for (int q = 0; q < 2; ++q) {
    const int f = lane + q * 64;
    h0[q] = (float)hop0[bn * 256 + f];
    h1[q] = (float)hop1[bn * 256 + f];
    h2[q] = (float)hop2[bn * 128 + f];
    const float sv = s[f];
    d0 += h0[q] * sv; d1 += h1[q] * sv; d2 += h2[q] * sv;
  }
  #pragma unroll
  for (int o = 32; o; o >>= 1) {
    d0 += __shfl_xor(d0, o); d1 += __shfl_xor(d1, o); d2 += __shfl_xor(d2, o);
  }
  const float mx = fmaxf(d0, fmaxf(d1, d2));
  float e0 = expf(d0 - mx), e1 = expf(d1 - mx), e2 = expf(d2 - mx);
  const float inv = 1.f / (e0 + e1 + e2);
  e0 *= inv; e1 *= inv; e2 *= inv;
  const float o0 = e0 * h0[0] + e1 * h1[0] + e2 * h2[0];   // fea[lane]
  const float o1 = e0 * h0[1] + e1 * h1[1] + e2 * h2[1];   // fea[lane+64] = r
  fea64[bn * 64 + lane] = (bf16)o0;
  // tem2[n][f]: f<2 -> x; f in [2,66) -> sigmoid(r[f-2]) * h[f-2]; else 0.
  const float r0 = __shfl(o1, (lane >= 2) ? lane - 2 : 0);
  const float r1 = __shfl(o1, (62 + lane) & 63);            // lanes 0,1 use it
  float t0 = 0.f, t1 = 0.f;
  if (nloc < 2000) {
    const long hb = (long)b * 128000 + (long)nloc * 64;
    if (lane < 2) {
      t0 = x[(long)b * 4000 + nloc * 2 + lane];
      t1 = (1.f / (1.f + expf(-r1))) * h[hb + 62 + lane];   // f = 64,65
    } else {
      t0 = (1.f / (1.f + expf(-r0))) * h[hb + (lane - 2)];
    }
  }
  tem[bn * 128 + lane] = (bf16)t0;
  tem[bn * 128 + 64 + lane] = (bf16)t1;
}

// g2 attention (F=64) fused with gru_out. c stays in register.
__global__ void attention_gru(const bf16* hop0, const bf16* hop1,
                              const bf16* hop2, const float* s,
                              const bf16* fea64, const float* h, float* out) {
  const int nloc = blockIdx.x * 4 + (threadIdx.x >> 6);
  const int b = blockIdx.y;
  const int lane = threadIdx.x & 63;
  const long bn = (long)b * 2048 + nloc;
  const float a0 = (float)hop0[bn * 128 + lane];
  const float a1 = (float)hop1[bn * 128 + lane];
  const float a2 = (float)hop2[bn * 64 + lane];
  const float sv = s[lane];
  float d0 = a0 * sv, d1 = a1 * sv, d2 = a2 * sv;
  #pragma unroll
  for (int o = 32; o; o >>= 1) {
    d0 += __shfl_xor(d0, o); d1 += __shfl_xor(d1, o); d2 += __shfl_xor(d2, o);
  }
  const float mx = fmaxf(d0, fmaxf(d1, d2));
  float e0 = expf(d0 - mx), e1 = expf(d1 - mx), e2 = expf(d2 - mx);
  const float inv = 1.f / (e0 + e1 + e2);
  e0 *= inv; e1 *= inv; e2 *= inv;
  const float c = e0 * a0 + e1 * a1 + e2 * a2;
  if (nloc < 2000) {
    const float z  = (float)fea64[bn * 64 + lane];
    const float hv = h[(long)b * 128000 + (long)nloc * 64 + lane];
    const float zs = 1.f / (1.f + expf(-z));
    out[(long)b * 128000 + (long)nloc * 64 + lane] =
        zs * hv + (1.f - zs) * tanhf(c);
  }
}

__global__ void ws_diag(float* out, int n, float v) {
  int i = blockIdx.x * blockDim.x + threadIdx.x;
  if (i < n) out[i] = v;
}

// ---------------------------------------------------------------------------

static TaskDesc TD(int kind, int gx, int nblk,
                   const bf16* A, int lda,
                   const bf16* B, int ldb, int zshB, long sB,
                   bf16* Cn, int ldcn, long sCn,
                   bf16* Ct, int ldct, long sCt, int zshC, int K) {
  TaskDesc t;
  t.g = GemmArgs{A, B, Cn, Ct, lda, ldb, ldcn, ldct, K, zshB, zshC, sB, sCn, sCt};
  t.kind = kind; t.gx = gx; t.blk0 = 0; t.nblk = nblk;
  return t;
}
static void run1(hipStream_t st, TaskDesc a) {
  MultiArgs m; m.t[0] = a; m.t[0].blk0 = 0; m.nt = 1;
  gemm_multi<<<a.nblk, 256, 0, st>>>(m);
}
static void run2p(hipStream_t st, TaskDesc a, TaskDesc b) {
  MultiArgs m; m.t[0] = a; m.t[0].blk0 = 0;
  m.t[1] = b; m.t[1].blk0 = a.nblk; m.nt = 2;
  gemm_multi<<<a.nblk + b.nblk, 256, 0, st>>>(m);
}

extern "C" void kernel_launch(void* const* d_in, const int* in_sizes, int n_in,
                              void* d_out, int out_size, void* d_ws, size_t ws_size,
                              hipStream_t stream) {
  const float* x    = (const float*)d_in[0];
  const float* hid  = (const float*)d_in[1];
  const float* S0   = (const float*)d_in[2];
  const float* S1   = (const float*)d_in[3];
  const float* M    = (const float*)d_in[4];

  char* base = (char*)d_ws;
  size_t off = 0;
  auto alloc = [&](size_t bytes) -> void* {
    void* r = base + off;
    off += (bytes + 255) & ~(size_t)255;
    return r;
  };

  bf16* S0b = (bf16*)alloc(2048ull * 2048 * 2);
  bf16* S1b = (bf16*)alloc(4096ull * 4096 * 2);
  bf16* Mb  = (bf16*)alloc(2048ull * 4096 * 2);
  bf16* MTb = (bf16*)alloc(4096ull * 2048 * 2);
  bf16* tem = (bf16*)alloc(16ull * 2048 * 128 * 2);   // stride 128

  // K-padded transposed weights (66->128 pad for 0,1,6,7)
  static const int wd[12][3] = {
    {66,128,128},{66,128,128},{256,128,256},{256,128,256},{128,128,128},{128,128,128},
    {66, 64,128},{66, 64,128},{128, 64,128},{128, 64,128},{ 64, 64, 64},{ 64, 64, 64}};
  static const int wsrc[12] = {5,6,7,8,9,10, 13,14,15,16,17,18};
  bf16* Wt[12];
  for (int i = 0; i < 12; ++i) Wt[i] = (bf16*)alloc((size_t)wd[i][1] * wd[i][2] * 2);
  float* s1 = (float*)alloc(128 * 4);
  float* s2 = (float*)alloc(64 * 4);

  const size_t SLOT = 16ull * 4096 * 128 * 2;  // 16 MB
  char* T0 = (char*)alloc(SLOT);
  char* T1 = (char*)alloc(SLOT);
  char* T2 = (char*)alloc(SLOT);
  char* T3 = (char*)alloc(SLOT);
  char* T4 = (char*)alloc(SLOT);

  if (off > ws_size) {
    ws_diag<<<4, 256, 0, stream>>>((float*)d_out, 1024, (float)(ws_size >> 20));
    return;
  }

  // g1 buffers (liveness identical to round 5):
  bf16* xW    = (bf16*)T0;               // [z][256][2048]
  bf16* eg0   = (bf16*)T1;               // [z][4096][128]
  bf16* cat1  = (bf16*)T2;               // [z][2048][256]
  bf16* eg0p  = (bf16*)T3;               // [z][128][4096]
  bf16* eg1nf = (bf16*)T4;               // [z][4096][128]
  bf16* eg1fn = (bf16*)T0;               // [z][128][4096]
  bf16* eg1p  = (bf16*)T3;               // [z][128][4096]
  bf16* cp1   = (bf16*)T1;               // [z][128][2048]
  bf16* eg2fn = (bf16*)T0;               // [z][128][4096]
  bf16* cat2  = (bf16*)T3;               // [z][2048][256]
  bf16* cp2   = (bf16*)T1;               // [z][128][2048]
  bf16* hop2  = (bf16*)(T1 + 8388608);   // [z][2048][128]
  bf16* fea64 = (bf16*)T4;               // [z][2048][64] (4MB, live to end)

  // ---- prep ----
  cvt_pad3<<<dim3(16, 8192), 256, 0, stream>>>(S0, S1, M, S0b, S1b, Mb);
  cvt_transpose<<<dim3(32, 64), dim3(64, 4), 0, stream>>>(M, 2000, 4000, MTb, 2048);
  WAll wa;
  for (int i = 0; i < 12; ++i)
    wa.w[i] = WPrep{(const float*)d_in[wsrc[i]], Wt[i], wd[i][0], wd[i][1], wd[i][2]};
  wa.aw1 = (const float*)d_in[11]; wa.al1 = (const float*)d_in[12]; wa.s1 = s1;
  wa.aw2 = (const float*)d_in[19]; wa.al2 = (const float*)d_in[20]; wa.s2 = s2;
  prep_weights<<<14, 256, 0, stream>>>(wa);
  build_tem1<<<dim3(1024, 16), 256, 0, stream>>>(x, hid, tem);

  // ---- g1 (F = 128; agg zshC=7, proj zshC=11/12) ----
  run1(stream, TD(0, 2, 512, Wt[0],128, tem,128,11,2048L*128,
                  xW,2048,256L*2048, nullptr,0,0, 11, 128));
  run2p(stream,
    TD(0, 32, 512, MTb,2048, xW,2048,7,256L*2048,
       eg0,128,4096L*128, nullptr,0,0, 7, 2048),
    TD(0, 16, 256, S0b,2048, xW+128*2048,2048,7,256L*2048,
       cat1,256,2048L*256, nullptr,0,0, 7, 2048));
  run1(stream, TD(0, 1, 512, Wt[4],128, eg0,128,12,4096L*128,
                  eg0p,4096,128L*4096, nullptr,0,0, 12, 128));
  run1(stream, TD(0, 32, 512, S1b,4096, eg0p,4096,7,128L*4096,
                  eg1nf,128,4096L*128, eg1fn,4096,128L*4096, 7, 4096));
  run2p(stream,
    TD(0, 16, 256, Mb,4096, eg1fn,4096,7,128L*4096,
       cat1+128,256,2048L*256, nullptr,0,0, 7, 4096),
    TD(0, 1, 512, Wt[5],128, eg1nf,128,12,4096L*128,
       eg1p,4096,128L*4096, nullptr,0,0, 12, 128));
  run2p(stream,
    TD(0, 32, 512, S1b,4096, eg1p,4096,7,128L*4096,
       nullptr,0,0, eg2fn,4096,128L*4096, 7, 4096),
    TD(0, 1, 256, Wt[2],256, cat1,256,11,2048L*256,
       cp1,2048,128L*2048, nullptr,0,0, 11, 256));
  run2p(stream,
    TD(0, 16, 256, Mb,4096, eg2fn,4096,7,128L*4096,
       cat2+128,256,2048L*256, nullptr,0,0, 7, 4096),
    TD(0, 16, 256, S0b,2048, cp1,2048,7,128L*2048,
       cat2,256,2048L*256, nullptr,0,0, 7, 2048));
  run1(stream, TD(0, 1, 256, Wt[3],256, cat2,256,11,2048L*256,
                  cp2,2048,128L*2048, nullptr,0,0, 11, 256));
  run1(stream, TD(0, 16, 256, S0b,2048, cp2,2048,7,128L*2048,
                  hop2,128,2048L*128, nullptr,0,0, 7, 2048));
  attention_fuse<<<dim3(512, 16), 256, 0, stream>>>(cat1, cat2, hop2, s1,
                                                    x, hid, fea64, tem);

  // g2 buffers (fea64 live at T4 lo):
  bf16* xW2     = (bf16*)T0;               // [z][128][2048]
  bf16* eg0_2   = (bf16*)T1;               // [z][4096][64]
  bf16* cat1_2  = (bf16*)T2;               // [z][2048][128]
  bf16* eg0p_2  = (bf16*)T3;               // [z][64][4096]
  bf16* eg1nf_2 = (bf16*)(T4 + 8388608);   // [z][4096][64]
  bf16* eg1fn_2 = (bf16*)T0;               // [z][64][4096]
  bf16* eg1p_2  = (bf16*)T3;               // [z][64][4096]
  bf16* cp1_2   = (bf16*)T1;               // [z][64][2048]
  bf16* eg2fn_2 = (bf16*)T0;               // [z][64][4096]
  bf16* cat2_2  = (bf16*)T3;               // [z][2048][128]
  bf16* cp2_2   = (bf16*)T1;               // [z][64][2048]
  bf16* hop2_2  = (bf16*)(T1 + 4194304);   // [z][2048][64]

  // ---- g2 (F = 64; agg zshC=6, proj zshC=11/12) ----
  run1(stream, TD(0, 1, 256, Wt[6],128, tem,128,11,2048L*128,
                  xW2,2048,128L*2048, nullptr,0,0, 11, 128));
  run2p(stream,
    TD(0, 32, 256, MTb,2048, xW2,2048,6,128L*2048,
       eg0_2,64,4096L*64, nullptr,0,0, 6, 2048),
    TD(0, 16, 128, S0b,2048, xW2+64*2048,2048,6,128L*2048,
       cat1_2,128,2048L*128, nullptr,0,0, 6, 2048));
  run1(stream, TD(1, 1, 512, Wt[10],64, eg0_2,64,12,4096L*64,
                  eg0p_2,4096,64L*4096, nullptr,0,0, 12, 64));
  run1(stream, TD(0, 32, 256, S1b,4096, eg0p_2,4096,6,64L*4096,
                  eg1nf_2,64,4096L*64, eg1fn_2,4096,64L*4096, 6, 4096));
  run2p(stream,
    TD(0, 16, 128, Mb,4096, eg1fn_2,4096,6,64L*4096,
       cat1_2+64,128,2048L*128, nullptr,0,0, 6, 4096),
    TD(1, 1, 512, Wt[11],64, eg1nf_2,64,12,4096L*64,
       eg1p_2,4096,64L*4096, nullptr,0,0, 12, 64));
  run2p(stream,
    TD(0, 32, 256, S1b,4096, eg1p_2,4096,6,64L*4096,
       nullptr,0,0, eg2fn_2,4096,64L*4096, 6, 4096),
    TD(1, 1, 256, Wt[8],128, cat1_2,128,11,2048L*128,
       cp1_2,2048,64L*2048, nullptr,0,0, 11, 128));
  run2p(stream,
    TD(0, 16, 128, Mb,4096, eg2fn_2,4096,6,64L*4096,
       cat2_2+64,128,2048L*128, nullptr,0,0, 6, 4096),
    TD(0, 16, 128, S0b,2048, cp1_2,2048,6,64L*2048,
       cat2_2,128,2048L*128, nullptr,0,0, 6, 2048));
  run1(stream, TD(1, 1, 256, Wt[9],128, cat2_2,128,11,2048L*128,
                  cp2_2,2048,64L*2048, nullptr,0,0, 11, 128));
  run1(stream, TD(0, 16, 128, S0b,2048, cp2_2,2048,6,64L*2048,
                  hop2_2,64,2048L*64, nullptr,0,0, 6, 2048));
  attention_gru<<<dim3(512, 16), 256, 0, stream>>>(cat1_2, cat2_2, hop2_2, s2,
                                                   fea64, hid, (float*)d_out);
}

// Round 7
// 650.488 us; speedup vs baseline: 1.5394x; 1.1979x over previous
//
#include <hip/hip_runtime.h>
#include <stdint.h>

// ---------------------------------------------------------------------------
// BGCGRU on MI355X. Round 7: algebraic collapse of the edge pipeline.
//   P1 = M*S1*M^T, P2 = M*S1^2*M^T precomputed (bf16 NT GEMMs, shared by
//   g1/g2/all batches); edge hops become node-space aggs with composite
//   weights We1=Wb*E0, We2=Wb*E0*E1. FLOPs 450->349 GF, better shapes.
// GEMM core unchanged from r5/r6 (2-phase dbuf, BK=64, XOR swizzle, z-fold,
// XCD M-stripe swizzle). Pads/transpose vectorized (float4 -> bf16x8).
// ---------------------------------------------------------------------------

typedef __bf16 bf16;
typedef float  f32x4  __attribute__((ext_vector_type(4)));
typedef __bf16 bf16x8 __attribute__((ext_vector_type(8)));
typedef __bf16 bf16x4v __attribute__((ext_vector_type(4)));

#define DEVI __device__ __forceinline__

DEVI void gload16(const bf16* g, bf16* l) {
  __builtin_amdgcn_global_load_lds(
      (const __attribute__((address_space(1))) void*)g,
      (__attribute__((address_space(3))) void*)l, 16, 0, 0);
}

struct GemmArgs {
  const bf16* A; const bf16* B;
  bf16* Cn;   // normal write:  [z] row-major [m][col], nullable
  bf16* Ct;   // transposed:    [z] row-major [col][m], nullable
  int lda, ldb, ldcn, ldct, K, zshB, zshC;
  long sB, sCn, sCt;   // per-z element strides
};

struct TaskDesc { GemmArgs g; int kind, gx, blk0, nblk; };
struct MultiArgs { TaskDesc t[2]; int nt; };

// 2-phase double-buffered NT GEMM, BK=64. 4 waves (2x2), 16x16x32 bf16 MFMA.
template<int BM, int BN>
DEVI void gemm_body(const GemmArgs& g, int bx, int by, bf16* smem) {
  constexpr int BK  = 64;
  constexpr int ASZ = BM * BK, BSZ = BN * BK;
  bf16* Abuf = smem;
  bf16* Bbuf = smem + 2 * ASZ;
  const int tid  = threadIdx.x;
  const int wave = tid >> 6;
  const int lane = tid & 63;
  const int wm = (wave >> 1) * (BM / 2);
  const int wn = (wave & 1) * (BN / 2);
  constexpr int FM = BM / 32;
  constexpr int FN = BN / 32;

  const int sseg = (((tid & 7) ^ ((tid >> 3) & 7))) * 8;  // swz source seg
  const int l15  = lane & 15;
  const int lq   = lane >> 4;

  const bf16* arow[BM / 32];
  #pragma unroll
  for (int c = 0; c < BM / 32; ++c)
    arow[c] = g.A + (long)(bx * BM + c * 32 + (tid >> 3)) * g.lda + sseg;
  const bf16* brow[BN / 32];
  const int maskB = (1 << g.zshB) - 1;
  #pragma unroll
  for (int c = 0; c < BN / 32; ++c) {
    const int nb = by * BN + c * 32 + (tid >> 3);
    brow[c] = g.B + (long)(nb >> g.zshB) * g.sB + (long)(nb & maskB) * g.ldb + sseg;
  }

  f32x4 acc[FM][FN] = {};

  auto stage = [&](int buf, int kt) {
    #pragma unroll
    for (int c = 0; c < BM / 32; ++c)
      gload16(arow[c] + kt, &Abuf[buf * ASZ + c * 2048 + tid * 8]);
    #pragma unroll
    for (int c = 0; c < BN / 32; ++c)
      gload16(brow[c] + kt, &Bbuf[buf * BSZ + c * 2048 + tid * 8]);
  };
  auto compute = [&](int cb) {
    #pragma unroll
    for (int kk = 0; kk < 2; ++kk) {
      bf16x8 af[FM], bfr[FN];
      #pragma unroll
      for (int i = 0; i < FM; ++i) {
        const int R = wm + i * 16 + l15;
        af[i] = *(const bf16x8*)
            &Abuf[cb * ASZ + R * 64 + ((kk * 4 + lq) ^ (l15 & 7)) * 8];
      }
      #pragma unroll
      for (int j = 0; j < FN; ++j) {
        const int R = wn + j * 16 + l15;
        bfr[j] = *(const bf16x8*)
            &Bbuf[cb * BSZ + R * 64 + ((kk * 4 + lq) ^ (l15 & 7)) * 8];
      }
      #pragma unroll
      for (int i = 0; i < FM; ++i)
        #pragma unroll
        for (int j = 0; j < FN; ++j)
          acc[i][j] = __builtin_amdgcn_mfma_f32_16x16x32_bf16(af[i], bfr[j],
                                                              acc[i][j], 0, 0, 0);
    }
  };

  const int nt = g.K / BK;
  stage(0, 0);
  __syncthreads();
  int cur = 0;
  for (int t = 0; t < nt; ++t) {
    if (t + 1 < nt) stage(cur ^ 1, (t + 1) * BK);
    compute(cur);
    __syncthreads();
    cur ^= 1;
  }

  const int gm0 = bx * BM + wm;
  const int gn0 = by * BN + wn;
  const int rowq = lq * 4;
  const int maskC = (1 << g.zshC) - 1;
  if (g.Cn) {
    #pragma unroll
    for (int i = 0; i < FM; ++i)
      #pragma unroll
      for (int j = 0; j < FN; ++j) {
        const int m0 = gm0 + i * 16 + rowq;
        const int ng = gn0 + j * 16 + l15;
        bf16* Cz = g.Cn + (long)(ng >> g.zshC) * g.sCn + (ng & maskC);
        #pragma unroll
        for (int r = 0; r < 4; ++r)
          Cz[(long)(m0 + r) * g.ldcn] = (bf16)acc[i][j][r];
      }
  }
  if (g.Ct) {
    #pragma unroll
    for (int i = 0; i < FM; ++i)
      #pragma unroll
      for (int j = 0; j < FN; ++j) {
        const int m0 = gm0 + i * 16 + rowq;
        const int ng = gn0 + j * 16 + l15;
        bf16x4v v = { (bf16)acc[i][j][0], (bf16)acc[i][j][1],
                      (bf16)acc[i][j][2], (bf16)acc[i][j][3] };
        *(bf16x4v*)(g.Ct + (long)(ng >> g.zshC) * g.sCt
                    + (long)(ng & maskC) * g.ldct + m0) = v;
      }
  }
}

__global__ __launch_bounds__(256) void gemm_multi(MultiArgs mu) {
  __shared__ bf16 smem[32768];    // 64 KB
  const int b = blockIdx.x;
  const int ti = (mu.nt > 1 && b >= mu.t[1].blk0) ? 1 : 0;
  const TaskDesc t = mu.t[ti];
  const int local = b - t.blk0;
  int bx, by;
  if ((t.gx & 7) == 0) {
    const int xcd = local & 7;
    const int idx = local >> 3;
    const int sub = t.gx >> 3;
    bx = xcd * sub + idx % sub;
    by = idx / sub;
  } else {
    bx = local % t.gx;
    by = local / t.gx;
  }
  if (t.kind == 0) gemm_body<128, 128>(t.g, bx, by, smem);
  else             gemm_body< 64, 128>(t.g, bx, by, smem);
}

// ---------------- prep / elementwise kernels -------------------------------

// Vectorized fp32 -> bf16 pad: 8 cols/thread. grid (Cp/2048, Rp).
__global__ void cvt_pad_v(const float* in, int R, int C, bf16* out, int Cp) {
  const int r = blockIdx.y;
  const int c0 = (blockIdx.x * blockDim.x + threadIdx.x) * 8;
  bf16x8 v;
  if (r < R && c0 + 7 < C) {
    const float4 a = *(const float4*)&in[(long)r * C + c0];
    const float4 b = *(const float4*)&in[(long)r * C + c0 + 4];
    v[0]=(bf16)a.x; v[1]=(bf16)a.y; v[2]=(bf16)a.z; v[3]=(bf16)a.w;
    v[4]=(bf16)b.x; v[5]=(bf16)b.y; v[6]=(bf16)b.z; v[7]=(bf16)b.w;
  } else {
    #pragma unroll
    for (int k = 0; k < 8; ++k) {
      const int c = c0 + k;
      v[k] = (bf16)((r < R && c < C) ? in[(long)r * C + c] : 0.f);
    }
  }
  *(bf16x8*)&out[(long)r * Cp + c0] = v;
}

// Vectorized tiled transpose+pad: out[c][r] = in[r][c]. grid (Rp/64, Cp/64).
__global__ void cvt_transpose_v(const float* in, int R, int C,
                                bf16* out, int ldo) {
  __shared__ float t[64][65];
  const int r0 = blockIdx.x * 64;   // in rows  = out cols
  const int c0 = blockIdx.y * 64;   // in cols  = out rows
  const int row = threadIdx.x >> 2;
  const int seg = (threadIdx.x & 3) * 16;
  const int r = r0 + row;
  #pragma unroll
  for (int q = 0; q < 4; ++q) {
    const int c = c0 + seg + q * 4;
    float4 a;
    if (r < R && c + 3 < C) a = *(const float4*)&in[(long)r * C + c];
    else {
      a.x = (r < R && c     < C) ? in[(long)r * C + c    ] : 0.f;
      a.y = (r < R && c + 1 < C) ? in[(long)r * C + c + 1] : 0.f;
      a.z = (r < R && c + 2 < C) ? in[(long)r * C + c + 2] : 0.f;
      a.w = (r < R && c + 3 < C) ? in[(long)r * C + c + 3] : 0.f;
    }
    t[seg + q * 4 + 0][row] = a.x;
    t[seg + q * 4 + 1][row] = a.y;
    t[seg + q * 4 + 2][row] = a.z;
    t[seg + q * 4 + 3][row] = a.w;
  }
  __syncthreads();
  const int orow = threadIdx.x >> 2;        // out row offset (= in col)
  const int oseg = (threadIdx.x & 3) * 16;  // out col offset (= in row)
  bf16x8 v0, v1;
  #pragma unroll
  for (int k = 0; k < 8; ++k) {
    v0[k] = (bf16)t[orow][oseg + k];
    v1[k] = (bf16)t[orow][oseg + 8 + k];
  }
  *(bf16x8*)&out[(long)(c0 + orow) * ldo + r0 + oseg] = v0;
  *(bf16x8*)&out[(long)(c0 + orow) * ldo + r0 + oseg + 8] = v1;
}

struct WPlain { const float* W; bf16* WT; int Fin, Fout, ldt; };
struct PrepArgs {
  WPlain w[6];
  const float* Wb1; const float* E0_1; bf16* We1T1;    // g1 [128][128]
  const float* Wbg2; const float* E0g2; bf16* We1T2;   // g2 [64][128]
  const float* aw1; const float* al1; float* s1;
  const float* aw2; const float* al2; float* s2;
};
__global__ void prep_weights(PrepArgs a) {
  const int b = blockIdx.x;
  if (b < 6) {
    WPlain w = a.w[b];
    for (int i = threadIdx.x; i < w.Fout * w.ldt; i += blockDim.x) {
      int c = i / w.ldt, f = i % w.ldt;
      float v = (f < w.Fin) ? w.W[(long)f * w.Fout + c] : 0.f;
      w.WT[i] = (bf16)v;
    }
  } else if (b < 10) {          // We1T1 = (Wb*E0)^T, c-chunk of 32
    for (int i = threadIdx.x; i < 32 * 128; i += blockDim.x) {
      int c = (b - 6) * 32 + i / 128, f = i % 128;
      float s = 0.f;
      if (f < 66)
        for (int k = 0; k < 128; ++k) s += a.E0_1[k * 128 + c] * a.Wb1[f * 128 + k];
      a.We1T1[c * 128 + f] = (bf16)s;
    }
  } else if (b == 10) {         // We1T2 (g2): [64][128]
    for (int i = threadIdx.x; i < 64 * 128; i += blockDim.x) {
      int c = i / 128, f = i % 128;
      float s = 0.f;
      if (f < 66)
        for (int k = 0; k < 64; ++k) s += a.E0g2[k * 64 + c] * a.Wbg2[f * 64 + k];
      a.We1T2[c * 128 + f] = (bf16)s;
    }
  } else if (b == 11) {
    for (int f = threadIdx.x; f < 128; f += blockDim.x) {
      float s = 0.f;
      for (int w = 0; w < 128; ++w) s += a.aw1[w * 128 + f] * a.al1[w];
      a.s1[f] = s;
    }
  } else {
    for (int f = threadIdx.x; f < 64; f += blockDim.x) {
      float s = 0.f;
      for (int w = 0; w < 64; ++w) s += a.aw2[w * 64 + f] * a.al2[w];
      a.s2[f] = s;
    }
  }
}

struct Prep2Args {
  const float* E1_1; bf16* We1T1; bf16* We2T1;
  const float* E1g2; bf16* We1T2; bf16* We2T2;
};
__global__ void prep_weights2(Prep2Args a) {   // We2^T = E1^T * We1^T
  const int b = blockIdx.x;
  if (b < 4) {
    for (int i = threadIdx.x; i < 32 * 128; i += blockDim.x) {
      int c = b * 32 + i / 128, f = i % 128;
      float s = 0.f;
      for (int k = 0; k < 128; ++k)
        s += a.E1_1[k * 128 + c] * (float)a.We1T1[k * 128 + f];
      a.We2T1[c * 128 + f] = (bf16)s;
    }
  } else {
    for (int i = threadIdx.x; i < 64 * 128; i += blockDim.x) {
      int c = i / 128, f = i % 128;
      float s = 0.f;
      for (int k = 0; k < 64; ++k)
        s += a.E1g2[k * 64 + c] * (float)a.We1T2[k * 128 + f];
      a.We2T2[c * 128 + f] = (bf16)s;
    }
  }
}

__global__ void build_tem1(const float* x, const float* h, bf16* tem) {
  const int b = blockIdx.y;
  const int i = blockIdx.x * blockDim.x + threadIdx.x;
  const int f = i & 127, n = i >> 7;
  float v = 0.f;
  if (n < 2000 && f < 66) {
    if (f < 2) v = x[(long)b * 4000 + n * 2 + f];
    else       v = h[(long)b * 128000 + (long)n * 64 + (f - 2)];
  }
  tem[((long)b * 2048 + n) * 128 + f] = (bf16)v;
}

// g1 attention (F=128) fused with build_tem2.
__global__ void attention_fuse(const bf16* hop0, const bf16* hop1,
                               const bf16* hop2, const float* s,
                               const float* x, const float* h,
                               bf16* fea64, bf16* tem) {
  const int nloc = blockIdx.x * 4 + (threadIdx.x >> 6);
  const int b = blockIdx.y;
  const int lane = threadIdx.x & 63;
  const long bn = (long)b * 2048 + nloc;
  float h0[2], h1[2], h2[2];
  float d0 = 0.f, d1 = 0.f, d2 = 0.f;
  #pragma unroll
  for (int q = 0; q < 2; ++q) {
    const int f = lane + q * 64;
    h0[q] = (float)hop0[bn * 256 + f];
    h1[q] = (float)hop1[bn * 256 + f];
    h2[q] = (float)hop2[bn * 128 + f];
    const float sv = s[f];
    d0 += h0[q] * sv; d1 += h1[q] * sv; d2 += h2[q] * sv;
  }
  #pragma unroll
  for (int o = 32; o; o >>= 1) {
    d0 += __shfl_xor(d0, o); d1 += __shfl_xor(d1, o); d2 += __shfl_xor(d2, o);
  }
  const float mx = fmaxf(d0, fmaxf(d1, d2));
  float e0 = expf(d0 - mx), e1 = expf(d1 - mx), e2 = expf(d2 - mx);
  const float inv = 1.f / (e0 + e1 + e2);
  e0 *= inv; e1 *= inv; e2 *= inv;
  const float o0 = e0 * h0[0] + e1 * h1[0] + e2 * h2[0];
  const float o1 = e0 * h0[1] + e1 * h1[1] + e2 * h2[1];   // r-gate
  fea64[bn * 64 + lane] = (bf16)o0;
  const float r0 = __shfl(o1, (lane >= 2) ? lane - 2 : 0);
  const float r1 = __shfl(o1, (62 + lane) & 63);
  float t0 = 0.f, t1 = 0.f;
  if (nloc < 2000) {
    const long hb = (long)b * 128000 + (long)nloc * 64;
    if (lane < 2) {
      t0 = x[(long)b * 4000 + nloc * 2 + lane];
      t1 = (1.f / (1.f + expf(-r1))) * h[hb + 62 + lane];
    } else {
      t0 = (1.f / (1.f + expf(-r0))) * h[hb + (lane - 2)];
    }
  }
  tem[bn * 128 + lane] = (bf16)t0;
  tem[bn * 128 + 64 + lane] = (bf16)t1;
}

// g2 attention (F=64) fused with gru_out.
__global__ void attention_gru(const bf16* hop0, const bf16* hop1,
                              const bf16* hop2, const float* s,
                              const bf16* fea64, const float* h, float* out) {
  const int nloc = blockIdx.x * 4 + (threadIdx.x >> 6);
  const int b = blockIdx.y;
  const int lane = threadIdx.x & 63;
  const long bn = (long)b * 2048 + nloc;
  const float a0 = (float)hop0[bn * 128 + lane];
  const float a1 = (float)hop1[bn * 128 + lane];
  const float a2 = (float)hop2[bn * 64 + lane];
  const float sv = s[lane];
  float d0 = a0 * sv, d1 = a1 * sv, d2 = a2 * sv;
  #pragma unroll
  for (int o = 32; o; o >>= 1) {
    d0 += __shfl_xor(d0, o); d1 += __shfl_xor(d1, o); d2 += __shfl_xor(d2, o);
  }
  const float mx = fmaxf(d0, fmaxf(d1, d2));
  float e0 = expf(d0 - mx), e1 = expf(d1 - mx), e2 = expf(d2 - mx);
  const float inv = 1.f / (e0 + e1 + e2);
  e0 *= inv; e1 *= inv; e2 *= inv;
  const float c = e0 * a0 + e1 * a1 + e2 * a2;
  if (nloc < 2000) {
    const float z  = (float)fea64[bn * 64 + lane];
    const float hv = h[(long)b * 128000 + (long)nloc * 64 + lane];
    const float zs = 1.f / (1.f + expf(-z));
    out[(long)b * 128000 + (long)nloc * 64 + lane] =
        zs * hv + (1.f - zs) * tanhf(c);
  }
}

__global__ void ws_diag(float* out, int n, float v) {
  int i = blockIdx.x * blockDim.x + threadIdx.x;
  if (i < n) out[i] = v;
}

// ---------------------------------------------------------------------------

static TaskDesc TD(int kind, int gx, int nblk,
                   const bf16* A, int lda,
                   const bf16* B, int ldb, int zshB, long sB,
                   bf16* Cn, int ldcn, long sCn,
                   bf16* Ct, int ldct, long sCt, int zshC, int K) {
  TaskDesc t;
  t.g = GemmArgs{A, B, Cn, Ct, lda, ldb, ldcn, ldct, K, zshB, zshC, sB, sCn, sCt};
  t.kind = kind; t.gx = gx; t.blk0 = 0; t.nblk = nblk;
  return t;
}
static void run1(hipStream_t st, TaskDesc a) {
  MultiArgs m; m.t[0] = a; m.t[0].blk0 = 0; m.nt = 1;
  gemm_multi<<<a.nblk, 256, 0, st>>>(m);
}
static void run2p(hipStream_t st, TaskDesc a, TaskDesc b) {
  MultiArgs m; m.t[0] = a; m.t[0].blk0 = 0;
  m.t[1] = b; m.t[1].blk0 = a.nblk; m.nt = 2;
  gemm_multi<<<a.nblk + b.nblk, 256, 0, st>>>(m);
}

extern "C" void kernel_launch(void* const* d_in, const int* in_sizes, int n_in,
                              void* d_out, int out_size, void* d_ws, size_t ws_size,
                              hipStream_t stream) {
  const float* x    = (const float*)d_in[0];
  const float* hid  = (const float*)d_in[1];
  const float* S0   = (const float*)d_in[2];
  const float* S1   = (const float*)d_in[3];
  const float* M    = (const float*)d_in[4];

  char* base = (char*)d_ws;
  size_t off = 0;
  auto alloc = [&](size_t bytes) -> void* {
    void* r = base + off;
    off += (bytes + 255) & ~(size_t)255;
    return r;
  };

  bf16* S0b  = (bf16*)alloc(2048ull * 2048 * 2);   //  8 MB
  bf16* S1b  = (bf16*)alloc(4096ull * 4096 * 2);   // 32 MB
  bf16* S1Tb = (bf16*)alloc(4096ull * 4096 * 2);   // 32 MB
  bf16* Mb   = (bf16*)alloc(2048ull * 4096 * 2);   // 16 MB
  bf16* tem  = (bf16*)alloc(16ull * 2048 * 128 * 2);  // 8 MB

  bf16* WtAll1 = (bf16*)alloc(384 * 128 * 2);  // W0^T | We1^T | We2^T (g1)
  bf16* W1T    = (bf16*)alloc(128 * 256 * 2);
  bf16* W2T    = (bf16*)alloc(128 * 256 * 2);
  bf16* WtAll2 = (bf16*)alloc(192 * 128 * 2);  // W0g2^T | We1g2^T | We2g2^T
  bf16* W1g2T  = (bf16*)alloc(64 * 128 * 2);
  bf16* W2g2T  = (bf16*)alloc(64 * 128 * 2);
  float* s1 = (float*)alloc(128 * 4);
  float* s2 = (float*)alloc(64 * 4);

  bf16* P1 = (bf16*)alloc(2048ull * 2048 * 2);     //  8 MB
  bf16* P2 = (bf16*)alloc(2048ull * 2048 * 2);     //  8 MB
  bf16* R  = (bf16*)alloc(2048ull * 4096 * 2);     // 16 MB
  bf16* R2 = (bf16*)alloc(2048ull * 4096 * 2);     // 16 MB (contig after R)

  if (off > ws_size) {
    ws_diag<<<4, 256, 0, stream>>>((float*)d_out, 1024, (float)(ws_size >> 20));
    return;
  }

  // Overlays (liveness-checked):
  bf16* cat1   = S1Tb;                               // 16 MB (after PR1)
  bf16* cat2   = (bf16*)((char*)S1Tb + 16777216);    // 16 MB
  bf16* xAll   = R;                                  // 24 MB (after PR2)
  bf16* cpb    = S1b;                                //  8 MB (after PR1)
  bf16* hop2   = (bf16*)((char*)S1b + 8388608);      //  8 MB
  bf16* fea64  = (bf16*)((char*)S1b + 16777216);     //  4 MB (live to end)
  bf16* xAll2  = R;                                  // 12 MB (g2)
  bf16* cat1_2 = S1Tb;                               //  8 MB
  bf16* cat2_2 = (bf16*)((char*)S1Tb + 8388608);     //  8 MB
  bf16* cpb2   = S1b;                                //  4 MB
  bf16* hop2_2 = (bf16*)((char*)S1b + 8388608);      //  4 MB

  // ---- prep (vectorized) ----
  cvt_pad_v<<<dim3(1, 2048), 256, 0, stream>>>(S0, 2000, 2000, S0b, 2048);
  cvt_pad_v<<<dim3(2, 4096), 256, 0, stream>>>(S1, 4000, 4000, S1b, 4096);
  cvt_pad_v<<<dim3(2, 2048), 256, 0, stream>>>(M, 2000, 4000, Mb, 4096);
  cvt_transpose_v<<<dim3(64, 64), 256, 0, stream>>>(S1, 4000, 4000, S1Tb, 4096);

  PrepArgs pa;
  pa.w[0] = WPlain{(const float*)d_in[6],  WtAll1,        66, 128, 128};
  pa.w[1] = WPlain{(const float*)d_in[7],  W1T,          256, 128, 256};
  pa.w[2] = WPlain{(const float*)d_in[8],  W2T,          256, 128, 256};
  pa.w[3] = WPlain{(const float*)d_in[14], WtAll2,        66,  64, 128};
  pa.w[4] = WPlain{(const float*)d_in[15], W1g2T,        128,  64, 128};
  pa.w[5] = WPlain{(const float*)d_in[16], W2g2T,        128,  64, 128};
  pa.Wb1 = (const float*)d_in[5];  pa.E0_1 = (const float*)d_in[9];
  pa.We1T1 = WtAll1 + 128 * 128;
  pa.Wbg2 = (const float*)d_in[13]; pa.E0g2 = (const float*)d_in[17];
  pa.We1T2 = WtAll2 + 64 * 128;
  pa.aw1 = (const float*)d_in[11]; pa.al1 = (const float*)d_in[12]; pa.s1 = s1;
  pa.aw2 = (const float*)d_in[19]; pa.al2 = (const float*)d_in[20]; pa.s2 = s2;
  prep_weights<<<13, 256, 0, stream>>>(pa);
  Prep2Args p2a{(const float*)d_in[10], WtAll1 + 128 * 128, WtAll1 + 256 * 128,
                (const float*)d_in[18], WtAll2 + 64 * 128,  WtAll2 + 128 * 128};
  prep_weights2<<<5, 256, 0, stream>>>(p2a);
  build_tem1<<<dim3(1024, 16), 256, 0, stream>>>(x, hid, tem);

  // ---- operator precompute: R = M*S1, R2 = M*S1^T, P1, P2 ----
  run2p(stream,
    TD(0, 16, 512, Mb,4096, S1Tb,4096,12,0, R,4096,0,  nullptr,0,0, 12, 4096),
    TD(0, 16, 512, Mb,4096, S1b,4096,12,0,  R2,4096,0, nullptr,0,0, 12, 4096));
  run2p(stream,
    TD(0, 16, 256, R,4096, Mb,4096,11,0, P1,2048,0, nullptr,0,0, 11, 4096),
    TD(0, 16, 256, R,4096, R2,4096,11,0, P2,2048,0, nullptr,0,0, 11, 4096));

  // ---- g1 ----
  // G1: xAll[z][384][2048] = [W0^T; We1^T; We2^T] x tem
  run1(stream, TD(0, 3, 768, WtAll1,128, tem,128,11,2048L*128,
                  xAll,2048,384L*2048, nullptr,0,0, 11, 128));
  // A2: cat1 = [S0*xW0 | P1*xe1]
  run2p(stream,
    TD(0, 16, 256, S0b,2048, xAll,2048,7,384L*2048,
       cat1,256,2048L*256, nullptr,0,0, 7, 2048),
    TD(0, 16, 256, P1,2048, xAll+128*2048,2048,7,384L*2048,
       cat1+128,256,2048L*256, nullptr,0,0, 7, 2048));
  // A3: cat2_hi = P2*xe2 ; cp1 = W1^T x cat1
  run2p(stream,
    TD(0, 16, 256, P2,2048, xAll+256*2048,2048,7,384L*2048,
       cat2+128,256,2048L*256, nullptr,0,0, 7, 2048),
    TD(0, 1, 256, W1T,256, cat1,256,11,2048L*256,
       cpb,2048,128L*2048, nullptr,0,0, 11, 256));
  // A4: cat2_lo = S0*cp1
  run1(stream, TD(0, 16, 256, S0b,2048, cpb,2048,7,128L*2048,
                  cat2,256,2048L*256, nullptr,0,0, 7, 2048));
  // A5: cp2 = W2^T x cat2
  run1(stream, TD(0, 1, 256, W2T,256, cat2,256,11,2048L*256,
                  cpb,2048,128L*2048, nullptr,0,0, 11, 256));
  // A6: hop2 = S0*cp2
  run1(stream, TD(0, 16, 256, S0b,2048, cpb,2048,7,128L*2048,
                  hop2,128,2048L*128, nullptr,0,0, 7, 2048));
  attention_fuse<<<dim3(512, 16), 256, 0, stream>>>(cat1, cat2, hop2, s1,
                                                    x, hid, fea64, tem);

  // ---- g2 ----
  run1(stream, TD(1, 3, 768, WtAll2,128, tem,128,11,2048L*128,
                  xAll2,2048,192L*2048, nullptr,0,0, 11, 128));
  run2p(stream,
    TD(0, 16, 128, S0b,2048, xAll2,2048,6,192L*2048,
       cat1_2,128,2048L*128, nullptr,0,0, 6, 2048),
    TD(0, 16, 128, P1,2048, xAll2+64*2048,2048,6,192L*2048,
       cat1_2+64,128,2048L*128, nullptr,0,0, 6, 2048));
  run2p(stream,
    TD(0, 16, 128, P2,2048, xAll2+128*2048,2048,6,192L*2048,
       cat2_2+64,128,2048L*128, nullptr,0,0, 6, 2048),
    TD(1, 1, 256, W1g2T,128, cat1_2,128,11,2048L*128,
       cpb2,2048,64L*2048, nullptr,0,0, 11, 128));
  run1(stream, TD(0, 16, 128, S0b,2048, cpb2,2048,6,64L*2048,
                  cat2_2,128,2048L*128, nullptr,0,0, 6, 2048));
  run1(stream, TD(1, 1, 256, W2g2T,128, cat2_2,128,11,2048L*128,
                  cpb2,2048,64L*2048, nullptr,0,0, 11, 128));
  run1(stream, TD(0, 16, 128, S0b,2048, cpb2,2048,6,64L*2048,
                  hop2_2,64,2048L*64, nullptr,0,0, 6, 2048));
  attention_gru<<<dim3(512, 16), 256, 0, stream>>>(cat1_2, cat2_2, hop2_2, s2,
                                                   fea64, hid, (float*)d_out);
}

// Round 8
// 633.121 us; speedup vs baseline: 1.5816x; 1.0274x over previous
//
#include <hip/hip_runtime.h>
#include <stdint.h>

// ---------------------------------------------------------------------------
// BGCGRU on MI355X. Round 8: dependency-packed multi-task launches.
//   - MultiArgs up to 3 tasks; independent GEMMs co-launched for occupancy.
//   - kind2 <128,64> tiles for g2 N=1024 aggs (256 blocks instead of 128).
//   - xAll moved to S1b overlay (dead after L1) so it can co-run with P1/P2.
//   - fused vectorized pad kernel (1 launch).
// GEMM core unchanged (2-phase dbuf, BK=64, XOR swizzle, z-fold, XCD stripe).
// ---------------------------------------------------------------------------

typedef __bf16 bf16;
typedef float  f32x4  __attribute__((ext_vector_type(4)));
typedef __bf16 bf16x8 __attribute__((ext_vector_type(8)));
typedef __bf16 bf16x4v __attribute__((ext_vector_type(4)));

#define DEVI __device__ __forceinline__

DEVI void gload16(const bf16* g, bf16* l) {
  __builtin_amdgcn_global_load_lds(
      (const __attribute__((address_space(1))) void*)g,
      (__attribute__((address_space(3))) void*)l, 16, 0, 0);
}

struct GemmArgs {
  const bf16* A; const bf16* B;
  bf16* Cn;   // normal write:  [z] row-major [m][col], nullable
  bf16* Ct;   // transposed:    [z] row-major [col][m], nullable
  int lda, ldb, ldcn, ldct, K, zshB, zshC;
  long sB, sCn, sCt;   // per-z element strides
};

struct TaskDesc { GemmArgs g; int kind, gx, blk0, nblk; };
struct MultiArgs { TaskDesc t[3]; int nt; };

// 2-phase double-buffered NT GEMM, BK=64. 4 waves (2x2), 16x16x32 bf16 MFMA.
template<int BM, int BN>
DEVI void gemm_body(const GemmArgs& g, int bx, int by, bf16* smem) {
  constexpr int BK  = 64;
  constexpr int ASZ = BM * BK, BSZ = BN * BK;
  bf16* Abuf = smem;
  bf16* Bbuf = smem + 2 * ASZ;
  const int tid  = threadIdx.x;
  const int wave = tid >> 6;
  const int lane = tid & 63;
  const int wm = (wave >> 1) * (BM / 2);
  const int wn = (wave & 1) * (BN / 2);
  constexpr int FM = BM / 32;
  constexpr int FN = BN / 32;

  const int sseg = (((tid & 7) ^ ((tid >> 3) & 7))) * 8;  // swz source seg
  const int l15  = lane & 15;
  const int lq   = lane >> 4;

  const bf16* arow[BM / 32];
  #pragma unroll
  for (int c = 0; c < BM / 32; ++c)
    arow[c] = g.A + (long)(bx * BM + c * 32 + (tid >> 3)) * g.lda + sseg;
  const bf16* brow[BN / 32];
  const int maskB = (1 << g.zshB) - 1;
  #pragma unroll
  for (int c = 0; c < BN / 32; ++c) {
    const int nb = by * BN + c * 32 + (tid >> 3);
    brow[c] = g.B + (long)(nb >> g.zshB) * g.sB + (long)(nb & maskB) * g.ldb + sseg;
  }

  f32x4 acc[FM][FN] = {};

  auto stage = [&](int buf, int kt) {
    #pragma unroll
    for (int c = 0; c < BM / 32; ++c)
      gload16(arow[c] + kt, &Abuf[buf * ASZ + c * 2048 + tid * 8]);
    #pragma unroll
    for (int c = 0; c < BN / 32; ++c)
      gload16(brow[c] + kt, &Bbuf[buf * BSZ + c * 2048 + tid * 8]);
  };
  auto compute = [&](int cb) {
    #pragma unroll
    for (int kk = 0; kk < 2; ++kk) {
      bf16x8 af[FM], bfr[FN];
      #pragma unroll
      for (int i = 0; i < FM; ++i) {
        const int R = wm + i * 16 + l15;
        af[i] = *(const bf16x8*)
            &Abuf[cb * ASZ + R * 64 + ((kk * 4 + lq) ^ (l15 & 7)) * 8];
      }
      #pragma unroll
      for (int j = 0; j < FN; ++j) {
        const int R = wn + j * 16 + l15;
        bfr[j] = *(const bf16x8*)
            &Bbuf[cb * BSZ + R * 64 + ((kk * 4 + lq) ^ (l15 & 7)) * 8];
      }
      #pragma unroll
      for (int i = 0; i < FM; ++i)
        #pragma unroll
        for (int j = 0; j < FN; ++j)
          acc[i][j] = __builtin_amdgcn_mfma_f32_16x16x32_bf16(af[i], bfr[j],
                                                              acc[i][j], 0, 0, 0);
    }
  };

  const int nt = g.K / BK;
  stage(0, 0);
  __syncthreads();
  int cur = 0;
  for (int t = 0; t < nt; ++t) {
    if (t + 1 < nt) stage(cur ^ 1, (t + 1) * BK);
    compute(cur);
    __syncthreads();
    cur ^= 1;
  }

  const int gm0 = bx * BM + wm;
  const int gn0 = by * BN + wn;
  const int rowq = lq * 4;
  const int maskC = (1 << g.zshC) - 1;
  if (g.Cn) {
    #pragma unroll
    for (int i = 0; i < FM; ++i)
      #pragma unroll
      for (int j = 0; j < FN; ++j) {
        const int m0 = gm0 + i * 16 + rowq;
        const int ng = gn0 + j * 16 + l15;
        bf16* Cz = g.Cn + (long)(ng >> g.zshC) * g.sCn + (ng & maskC);
        #pragma unroll
        for (int r = 0; r < 4; ++r)
          Cz[(long)(m0 + r) * g.ldcn] = (bf16)acc[i][j][r];
      }
  }
  if (g.Ct) {
    #pragma unroll
    for (int i = 0; i < FM; ++i)
      #pragma unroll
      for (int j = 0; j < FN; ++j) {
        const int m0 = gm0 + i * 16 + rowq;
        const int ng = gn0 + j * 16 + l15;
        bf16x4v v = { (bf16)acc[i][j][0], (bf16)acc[i][j][1],
                      (bf16)acc[i][j][2], (bf16)acc[i][j][3] };
        *(bf16x4v*)(g.Ct + (long)(ng >> g.zshC) * g.sCt
                    + (long)(ng & maskC) * g.ldct + m0) = v;
      }
  }
}

__global__ __launch_bounds__(256) void gemm_multi(MultiArgs mu) {
  __shared__ bf16 smem[32768];    // 64 KB
  const int b = blockIdx.x;
  int ti = 0;
  if (mu.nt > 1 && b >= mu.t[1].blk0) ti = 1;
  if (mu.nt > 2 && b >= mu.t[2].blk0) ti = 2;
  const TaskDesc t = mu.t[ti];
  const int local = b - t.blk0;
  int bx, by;
  if ((t.gx & 7) == 0) {
    const int xcd = local & 7;
    const int idx = local >> 3;
    const int sub = t.gx >> 3;
    bx = xcd * sub + idx % sub;
    by = idx / sub;
  } else {
    bx = local % t.gx;
    by = local / t.gx;
  }
  if (t.kind == 0)      gemm_body<128, 128>(t.g, bx, by, smem);
  else if (t.kind == 1) gemm_body< 64, 128>(t.g, bx, by, smem);
  else                  gemm_body<128,  64>(t.g, bx, by, smem);
}

// ---------------- prep / elementwise kernels -------------------------------

// Fused vectorized pads: y 0..2047 -> S0, 2048..6143 -> S1, 6144..8191 -> M.
__global__ void cvt_pad_all(const float* S0, const float* S1, const float* M,
                            bf16* S0b, bf16* S1b, bf16* Mb) {
  const int y = blockIdx.y;
  const int c0 = (blockIdx.x * blockDim.x + threadIdx.x) * 8;
  const float* in; bf16* out; int R, C, Cp, r;
  if (y < 2048)      { in = S0; out = S0b; R = 2000; C = 2000; Cp = 2048; r = y; }
  else if (y < 6144) { in = S1; out = S1b; R = 4000; C = 4000; Cp = 4096; r = y - 2048; }
  else               { in = M;  out = Mb;  R = 2000; C = 4000; Cp = 4096; r = y - 6144; }
  if (c0 >= Cp) return;
  bf16x8 v;
  if (r < R && c0 + 7 < C) {
    const float4 a = *(const float4*)&in[(long)r * C + c0];
    const float4 b = *(const float4*)&in[(long)r * C + c0 + 4];
    v[0]=(bf16)a.x; v[1]=(bf16)a.y; v[2]=(bf16)a.z; v[3]=(bf16)a.w;
    v[4]=(bf16)b.x; v[5]=(bf16)b.y; v[6]=(bf16)b.z; v[7]=(bf16)b.w;
  } else {
    #pragma unroll
    for (int k = 0; k < 8; ++k) {
      const int c = c0 + k;
      v[k] = (bf16)((r < R && c < C) ? in[(long)r * C + c] : 0.f);
    }
  }
  *(bf16x8*)&out[(long)r * Cp + c0] = v;
}

// Vectorized tiled transpose+pad: out[c][r] = in[r][c]. grid (Rp/64, Cp/64).
__global__ void cvt_transpose_v(const float* in, int R, int C,
                                bf16* out, int ldo) {
  __shared__ float t[64][65];
  const int r0 = blockIdx.x * 64;
  const int c0 = blockIdx.y * 64;
  const int row = threadIdx.x >> 2;
  const int seg = (threadIdx.x & 3) * 16;
  const int r = r0 + row;
  #pragma unroll
  for (int q = 0; q < 4; ++q) {
    const int c = c0 + seg + q * 4;
    float4 a;
    if (r < R && c + 3 < C) a = *(const float4*)&in[(long)r * C + c];
    else {
      a.x = (r < R && c     < C) ? in[(long)r * C + c    ] : 0.f;
      a.y = (r < R && c + 1 < C) ? in[(long)r * C + c + 1] : 0.f;
      a.z = (r < R && c + 2 < C) ? in[(long)r * C + c + 2] : 0.f;
      a.w = (r < R && c + 3 < C) ? in[(long)r * C + c + 3] : 0.f;
    }
    t[seg + q * 4 + 0][row] = a.x;
    t[seg + q * 4 + 1][row] = a.y;
    t[seg + q * 4 + 2][row] = a.z;
    t[seg + q * 4 + 3][row] = a.w;
  }
  __syncthreads();
  const int orow = threadIdx.x >> 2;
  const int oseg = (threadIdx.x & 3) * 16;
  bf16x8 v0, v1;
  #pragma unroll
  for (int k = 0; k < 8; ++k) {
    v0[k] = (bf16)t[orow][oseg + k];
    v1[k] = (bf16)t[orow][oseg + 8 + k];
  }
  *(bf16x8*)&out[(long)(c0 + orow) * ldo + r0 + oseg] = v0;
  *(bf16x8*)&out[(long)(c0 + orow) * ldo + r0 + oseg + 8] = v1;
}

struct WPlain { const float* W; bf16* WT; int Fin, Fout, ldt; };
struct PrepArgs {
  WPlain w[6];
  const float* Wb1; const float* E0_1; bf16* We1T1;
  const float* Wbg2; const float* E0g2; bf16* We1T2;
  const float* aw1; const float* al1; float* s1;
  const float* aw2; const float* al2; float* s2;
};
__global__ void prep_weights(PrepArgs a) {
  const int b = blockIdx.x;
  if (b < 6) {
    WPlain w = a.w[b];
    for (int i = threadIdx.x; i < w.Fout * w.ldt; i += blockDim.x) {
      int c = i / w.ldt, f = i % w.ldt;
      float v = (f < w.Fin) ? w.W[(long)f * w.Fout + c] : 0.f;
      w.WT[i] = (bf16)v;
    }
  } else if (b < 10) {
    for (int i = threadIdx.x; i < 32 * 128; i += blockDim.x) {
      int c = (b - 6) * 32 + i / 128, f = i % 128;
      float s = 0.f;
      if (f < 66)
        for (int k = 0; k < 128; ++k) s += a.E0_1[k * 128 + c] * a.Wb1[f * 128 + k];
      a.We1T1[c * 128 + f] = (bf16)s;
    }
  } else if (b == 10) {
    for (int i = threadIdx.x; i < 64 * 128; i += blockDim.x) {
      int c = i / 128, f = i % 128;
      float s = 0.f;
      if (f < 66)
        for (int k = 0; k < 64; ++k) s += a.E0g2[k * 64 + c] * a.Wbg2[f * 64 + k];
      a.We1T2[c * 128 + f] = (bf16)s;
    }
  } else if (b == 11) {
    for (int f = threadIdx.x; f < 128; f += blockDim.x) {
      float s = 0.f;
      for (int w = 0; w < 128; ++w) s += a.aw1[w * 128 + f] * a.al1[w];
      a.s1[f] = s;
    }
  } else {
    for (int f = threadIdx.x; f < 64; f += blockDim.x) {
      float s = 0.f;
      for (int w = 0; w < 64; ++w) s += a.aw2[w * 64 + f] * a.al2[w];
      a.s2[f] = s;
    }
  }
}

struct Prep2Args {
  const float* E1_1; bf16* We1T1; bf16* We2T1;
  const float* E1g2; bf16* We1T2; bf16* We2T2;
};
__global__ void prep_weights2(Prep2Args a) {
  const int b = blockIdx.x;
  if (b < 4) {
    for (int i = threadIdx.x; i < 32 * 128; i += blockDim.x) {
      int c = b * 32 + i / 128, f = i % 128;
      float s = 0.f;
      for (int k = 0; k < 128; ++k)
        s += a.E1_1[k * 128 + c] * (float)a.We1T1[k * 128 + f];
      a.We2T1[c * 128 + f] = (bf16)s;
    }
  } else {
    for (int i = threadIdx.x; i < 64 * 128; i += blockDim.x) {
      int c = i / 128, f = i % 128;
      float s = 0.f;
      for (int k = 0; k < 64; ++k)
        s += a.E1g2[k * 64 + c] * (float)a.We1T2[k * 128 + f];
      a.We2T2[c * 128 + f] = (bf16)s;
    }
  }
}

__global__ void build_tem1(const float* x, const float* h, bf16* tem) {
  const int b = blockIdx.y;
  const int i = blockIdx.x * blockDim.x + threadIdx.x;
  const int f = i & 127, n = i >> 7;
  float v = 0.f;
  if (n < 2000 && f < 66) {
    if (f < 2) v = x[(long)b * 4000 + n * 2 + f];
    else       v = h[(long)b * 128000 + (long)n * 64 + (f - 2)];
  }
  tem[((long)b * 2048 + n) * 128 + f] = (bf16)v;
}

// g1 attention (F=128) fused with build_tem2.
__global__ void attention_fuse(const bf16* hop0, const bf16* hop1,
                               const bf16* hop2, const float* s,
                               const float* x, const float* h,
                               bf16* fea64, bf16* tem) {
  const int nloc = blockIdx.x * 4 + (threadIdx.x >> 6);
  const int b = blockIdx.y;
  const int lane = threadIdx.x & 63;
  const long bn = (long)b * 2048 + nloc;
  float h0[2], h1[2], h2[2];
  float d0 = 0.f, d1 = 0.f, d2 = 0.f;
  #pragma unroll
  for (int q = 0; q < 2; ++q) {
    const int f = lane + q * 64;
    h0[q] = (float)hop0[bn * 256 + f];
    h1[q] = (float)hop1[bn * 256 + f];
    h2[q] = (float)hop2[bn * 128 + f];
    const float sv = s[f];
    d0 += h0[q] * sv; d1 += h1[q] * sv; d2 += h2[q] * sv;
  }
  #pragma unroll
  for (int o = 32; o; o >>= 1) {
    d0 += __shfl_xor(d0, o); d1 += __shfl_xor(d1, o); d2 += __shfl_xor(d2, o);
  }
  const float mx = fmaxf(d0, fmaxf(d1, d2));
  float e0 = expf(d0 - mx), e1 = expf(d1 - mx), e2 = expf(d2 - mx);
  const float inv = 1.f / (e0 + e1 + e2);
  e0 *= inv; e1 *= inv; e2 *= inv;
  const float o0 = e0 * h0[0] + e1 * h1[0] + e2 * h2[0];
  const float o1 = e0 * h0[1] + e1 * h1[1] + e2 * h2[1];   // r-gate
  fea64[bn * 64 + lane] = (bf16)o0;
  const float r0 = __shfl(o1, (lane >= 2) ? lane - 2 : 0);
  const float r1 = __shfl(o1, (62 + lane) & 63);
  float t0 = 0.f, t1 = 0.f;
  if (nloc < 2000) {
    const long hb = (long)b * 128000 + (long)nloc * 64;
    if (lane < 2) {
      t0 = x[(long)b * 4000 + nloc * 2 + lane];
      t1 = (1.f / (1.f + expf(-r1))) * h[hb + 62 + lane];
    } else {
      t0 = (1.f / (1.f + expf(-r0))) * h[hb + (lane - 2)];
    }
  }
  tem[bn * 128 + lane] = (bf16)t0;
  tem[bn * 128 + 64 + lane] = (bf16)t1;
}

// g2 attention (F=64) fused with gru_out.
__global__ void attention_gru(const bf16* hop0, const bf16* hop1,
                              const bf16* hop2, const float* s,
                              const bf16* fea64, const float* h, float* out) {
  const int nloc = blockIdx.x * 4 + (threadIdx.x >> 6);
  const int b = blockIdx.y;
  const int lane = threadIdx.x & 63;
  const long bn = (long)b * 2048 + nloc;
  const float a0 = (float)hop0[bn * 128 + lane];
  const float a1 = (float)hop1[bn * 128 + lane];
  const float a2 = (float)hop2[bn * 64 + lane];
  const float sv = s[lane];
  float d0 = a0 * sv, d1 = a1 * sv, d2 = a2 * sv;
  #pragma unroll
  for (int o = 32; o; o >>= 1) {
    d0 += __shfl_xor(d0, o); d1 += __shfl_xor(d1, o); d2 += __shfl_xor(d2, o);
  }
  const float mx = fmaxf(d0, fmaxf(d1, d2));
  float e0 = expf(d0 - mx), e1 = expf(d1 - mx), e2 = expf(d2 - mx);
  const float inv = 1.f / (e0 + e1 + e2);
  e0 *= inv; e1 *= inv; e2 *= inv;
  const float c = e0 * a0 + e1 * a1 + e2 * a2;
  if (nloc < 2000) {
    const float z  = (float)fea64[bn * 64 + lane];
    const float hv = h[(long)b * 128000 + (long)nloc * 64 + lane];
    const float zs = 1.f / (1.f + expf(-z));
    out[(long)b * 128000 + (long)nloc * 64 + lane] =
        zs * hv + (1.f - zs) * tanhf(c);
  }
}

__global__ void ws_diag(float* out, int n, float v) {
  int i = blockIdx.x * blockDim.x + threadIdx.x;
  if (i < n) out[i] = v;
}

// ---------------------------------------------------------------------------

static TaskDesc TD(int kind, int gx, int nblk,
                   const bf16* A, int lda,
                   const bf16* B, int ldb, int zshB, long sB,
                   bf16* Cn, int ldcn, long sCn,
                   bf16* Ct, int ldct, long sCt, int zshC, int K) {
  TaskDesc t;
  t.g = GemmArgs{A, B, Cn, Ct, lda, ldb, ldcn, ldct, K, zshB, zshC, sB, sCn, sCt};
  t.kind = kind; t.gx = gx; t.blk0 = 0; t.nblk = nblk;
  return t;
}
static void runT(hipStream_t st, int n, const TaskDesc* ts) {
  MultiArgs m; int off = 0;
  for (int i = 0; i < n; ++i) { m.t[i] = ts[i]; m.t[i].blk0 = off; off += ts[i].nblk; }
  m.nt = n;
  gemm_multi<<<off, 256, 0, st>>>(m);
}
static void run1(hipStream_t st, TaskDesc a) { runT(st, 1, &a); }
static void run2p(hipStream_t st, TaskDesc a, TaskDesc b) {
  TaskDesc ts[2] = {a, b}; runT(st, 2, ts);
}
static void run3p(hipStream_t st, TaskDesc a, TaskDesc b, TaskDesc c) {
  TaskDesc ts[3] = {a, b, c}; runT(st, 3, ts);
}

extern "C" void kernel_launch(void* const* d_in, const int* in_sizes, int n_in,
                              void* d_out, int out_size, void* d_ws, size_t ws_size,
                              hipStream_t stream) {
  const float* x    = (const float*)d_in[0];
  const float* hid  = (const float*)d_in[1];
  const float* S0   = (const float*)d_in[2];
  const float* S1   = (const float*)d_in[3];
  const float* M    = (const float*)d_in[4];

  char* base = (char*)d_ws;
  size_t off = 0;
  auto alloc = [&](size_t bytes) -> void* {
    void* r = base + off;
    off += (bytes + 255) & ~(size_t)255;
    return r;
  };

  bf16* S0b  = (bf16*)alloc(2048ull * 2048 * 2);   //  8 MB
  bf16* S1b  = (bf16*)alloc(4096ull * 4096 * 2);   // 32 MB
  bf16* S1Tb = (bf16*)alloc(4096ull * 4096 * 2);   // 32 MB
  bf16* Mb   = (bf16*)alloc(2048ull * 4096 * 2);   // 16 MB
  bf16* tem  = (bf16*)alloc(16ull * 2048 * 128 * 2);  // 8 MB

  bf16* WtAll1 = (bf16*)alloc(384 * 128 * 2);
  bf16* W1T    = (bf16*)alloc(128 * 256 * 2);
  bf16* W2T    = (bf16*)alloc(128 * 256 * 2);
  bf16* WtAll2 = (bf16*)alloc(192 * 128 * 2);
  bf16* W1g2T  = (bf16*)alloc(64 * 128 * 2);
  bf16* W2g2T  = (bf16*)alloc(64 * 128 * 2);
  float* s1 = (float*)alloc(128 * 4);
  float* s2 = (float*)alloc(64 * 4);

  bf16* P1 = (bf16*)alloc(2048ull * 2048 * 2);     //  8 MB
  bf16* P2 = (bf16*)alloc(2048ull * 2048 * 2);     //  8 MB
  bf16* R  = (bf16*)alloc(2048ull * 4096 * 2);     // 16 MB
  bf16* R2 = (bf16*)alloc(2048ull * 4096 * 2);     // 16 MB

  if (off > ws_size) {
    ws_diag<<<4, 256, 0, stream>>>((float*)d_out, 1024, (float)(ws_size >> 20));
    return;
  }

  // Overlays (liveness-audited):
  // S1b (dead after L1): xAll [0:25.2MB] (L2-L3); then cpb [0:8] (L4+),
  //   hop2 [8:16] (L7+), fea64 [16:20] (attn->end), cpb2 [0:4], hop2_2 [8:12].
  // S1Tb (dead after L1): cat1 [0:16], cat2 [16:32]; g2: cat1_2 [0:8],
  //   cat2_2 [8:16] (after attn_fuse).
  // R (dead after L2): xAll2 [0:12.6MB] (L8+).
  bf16* xAll   = S1b;
  bf16* cat1   = S1Tb;
  bf16* cat2   = (bf16*)((char*)S1Tb + 16777216);
  bf16* cpb    = S1b;
  bf16* hop2   = (bf16*)((char*)S1b + 8388608);
  bf16* fea64  = (bf16*)((char*)S1b + 16777216);
  bf16* xAll2  = R;
  bf16* cat1_2 = S1Tb;
  bf16* cat2_2 = (bf16*)((char*)S1Tb + 8388608);
  bf16* cpb2   = S1b;
  bf16* hop2_2 = (bf16*)((char*)S1b + 8388608);

  // ---- prep ----
  cvt_pad_all<<<dim3(2, 8192), 256, 0, stream>>>(S0, S1, M, S0b, S1b, Mb);
  cvt_transpose_v<<<dim3(64, 64), 256, 0, stream>>>(S1, 4000, 4000, S1Tb, 4096);

  PrepArgs pa;
  pa.w[0] = WPlain{(const float*)d_in[6],  WtAll1,  66, 128, 128};
  pa.w[1] = WPlain{(const float*)d_in[7],  W1T,    256, 128, 256};
  pa.w[2] = WPlain{(const float*)d_in[8],  W2T,    256, 128, 256};
  pa.w[3] = WPlain{(const float*)d_in[14], WtAll2,  66,  64, 128};
  pa.w[4] = WPlain{(const float*)d_in[15], W1g2T,  128,  64, 128};
  pa.w[5] = WPlain{(const float*)d_in[16], W2g2T,  128,  64, 128};
  pa.Wb1 = (const float*)d_in[5];  pa.E0_1 = (const float*)d_in[9];
  pa.We1T1 = WtAll1 + 128 * 128;
  pa.Wbg2 = (const float*)d_in[13]; pa.E0g2 = (const float*)d_in[17];
  pa.We1T2 = WtAll2 + 64 * 128;
  pa.aw1 = (const float*)d_in[11]; pa.al1 = (const float*)d_in[12]; pa.s1 = s1;
  pa.aw2 = (const float*)d_in[19]; pa.al2 = (const float*)d_in[20]; pa.s2 = s2;
  prep_weights<<<13, 256, 0, stream>>>(pa);
  Prep2Args p2a{(const float*)d_in[10], WtAll1 + 128 * 128, WtAll1 + 256 * 128,
                (const float*)d_in[18], WtAll2 + 64 * 128,  WtAll2 + 128 * 128};
  prep_weights2<<<5, 256, 0, stream>>>(p2a);
  build_tem1<<<dim3(1024, 16), 256, 0, stream>>>(x, hid, tem);

  // ---- L1: R = M*S1, R2 = M*S1^T ----
  run2p(stream,
    TD(0, 16, 512, Mb,4096, S1Tb,4096,12,0, R,4096,0,  nullptr,0,0, 12, 4096),
    TD(0, 16, 512, Mb,4096, S1b,4096,12,0,  R2,4096,0, nullptr,0,0, 12, 4096));
  // ---- L2: P1 = R*M^T, P2 = R*R2^T, xAll proj (independent; S1b now dead) --
  run3p(stream,
    TD(0, 16, 256, R,4096, Mb,4096,11,0, P1,2048,0, nullptr,0,0, 11, 4096),
    TD(0, 16, 256, R,4096, R2,4096,11,0, P2,2048,0, nullptr,0,0, 11, 4096),
    TD(0, 3, 768, WtAll1,128, tem,128,11,2048L*128,
       xAll,2048,384L*2048, nullptr,0,0, 11, 128));
  // ---- L3: cat1 = [S0*xW0 | P1*xe1], cat2_hi = P2*xe2 ----
  run3p(stream,
    TD(0, 16, 256, S0b,2048, xAll,2048,7,384L*2048,
       cat1,256,2048L*256, nullptr,0,0, 7, 2048),
    TD(0, 16, 256, P1,2048, xAll+128*2048,2048,7,384L*2048,
       cat1+128,256,2048L*256, nullptr,0,0, 7, 2048),
    TD(0, 16, 256, P2,2048, xAll+256*2048,2048,7,384L*2048,
       cat2+128,256,2048L*256, nullptr,0,0, 7, 2048));
  // ---- L4-L7: serial g1 tail ----
  run1(stream, TD(0, 1, 256, W1T,256, cat1,256,11,2048L*256,
                  cpb,2048,128L*2048, nullptr,0,0, 11, 256));
  run1(stream, TD(0, 16, 256, S0b,2048, cpb,2048,7,128L*2048,
                  cat2,256,2048L*256, nullptr,0,0, 7, 2048));
  run1(stream, TD(0, 1, 256, W2T,256, cat2,256,11,2048L*256,
                  cpb,2048,128L*2048, nullptr,0,0, 11, 256));
  run1(stream, TD(0, 16, 256, S0b,2048, cpb,2048,7,128L*2048,
                  hop2,128,2048L*128, nullptr,0,0, 7, 2048));
  attention_fuse<<<dim3(512, 16), 256, 0, stream>>>(cat1, cat2, hop2, s1,
                                                    x, hid, fea64, tem);

  // ---- L8: g2 projection ----
  run1(stream, TD(1, 3, 768, WtAll2,128, tem,128,11,2048L*128,
                  xAll2,2048,192L*2048, nullptr,0,0, 11, 128));
  // ---- L9: cat1_2 = [S0*xW0 | P1*xe1], cat2_2 hi = P2*xe2 (kind2 tiles) ----
  run3p(stream,
    TD(2, 16, 256, S0b,2048, xAll2,2048,6,192L*2048,
       cat1_2,128,2048L*128, nullptr,0,0, 6, 2048),
    TD(2, 16, 256, P1,2048, xAll2+64*2048,2048,6,192L*2048,
       cat1_2+64,128,2048L*128, nullptr,0,0, 6, 2048),
    TD(2, 16, 256, P2,2048, xAll2+128*2048,2048,6,192L*2048,
       cat2_2+64,128,2048L*128, nullptr,0,0, 6, 2048));
  // ---- L10-L13: serial g2 tail ----
  run1(stream, TD(1, 1, 256, W1g2T,128, cat1_2,128,11,2048L*128,
                  cpb2,2048,64L*2048, nullptr,0,0, 11, 128));
  run1(stream, TD(2, 16, 256, S0b,2048, cpb2,2048,6,64L*2048,
                  cat2_2,128,2048L*128, nullptr,0,0, 6, 2048));
  run1(stream, TD(1, 1, 256, W2g2T,128, cat2_2,128,11,2048L*128,
                  cpb2,2048,64L*2048, nullptr,0,0, 11, 128));
  run1(stream, TD(2, 16, 256, S0b,2048, cpb2,2048,6,64L*2048,
                  hop2_2,64,2048L*64, nullptr,0,0, 6, 2048));
  attention_gru<<<dim3(512, 16), 256, 0, stream>>>(cat1_2, cat2_2, hop2_2, s2,
                                                   fea64, hid, (float*)d_out);
}